// Round 14
// baseline (740.035 us; speedup 1.0000x reference)
//
#include <hip/hip_runtime.h>
#include <hip/hip_bf16.h>
#include <utility>

// Shapes: b=4, n=8192, d=512, h=8, dh=64, m=256 landmarks, l=32, conv k=33. bh=32.
// Round 14: flash1 split-KV 8 -> 16 (512 -> 1024 blocks; latency-bound kernel
// gets 2x TLP). Partials: pOT -> ARh..FTl (33.55MB), pM/pL -> zBth/zBtl.

typedef unsigned short ushort_t;
typedef __attribute__((ext_vector_type(8))) short short8;
typedef __attribute__((ext_vector_type(4))) float f32x4;
typedef __attribute__((ext_vector_type(16))) float f32x16;

#define GPTR(p) ((const __attribute__((address_space(1))) void*)(p))
#define LPTR(p) ((__attribute__((address_space(3))) void*)(p))

__device__ inline float bf2f(ushort_t u) {
  union { unsigned int i; float f; } x; x.i = ((unsigned int)u) << 16; return x.f;
}
__device__ inline ushort_t f2bf(float f) {
  union { float f; unsigned int i; } x; x.f = f;
  unsigned int r = x.i + 0x7FFF + ((x.i >> 16) & 1);   // round-nearest-even
  return (ushort_t)(r >> 16);
}

// ---------------- LayerNorm -> bf16 [32768][512] ----------------
__global__ __launch_bounds__(256) void ln_bf16(const float* __restrict__ x,
                                               const float* __restrict__ g,
                                               const float* __restrict__ be,
                                               ushort_t* __restrict__ out) {
  int row = blockIdx.x; int t = threadIdx.x;
  const float* xr = x + (size_t)row * 512;
  float2 v = *(const float2*)(xr + 2 * t);
  float s = v.x + v.y, qs = v.x * v.x + v.y * v.y;
#pragma unroll
  for (int o = 32; o > 0; o >>= 1) { s += __shfl_xor(s, o); qs += __shfl_xor(qs, o); }
  __shared__ float ps[4], pq[4];
  if ((t & 63) == 0) { ps[t >> 6] = s; pq[t >> 6] = qs; }
  __syncthreads();
  s = ps[0] + ps[1] + ps[2] + ps[3];
  qs = pq[0] + pq[1] + pq[2] + pq[3];
  float mu = s * (1.f / 512.f);
  float var = qs * (1.f / 512.f) - mu * mu;
  float rstd = rsqrtf(var + 1e-5f);
  float o0 = (v.x - mu) * rstd * g[2 * t] + be[2 * t];
  float o1 = (v.y - mu) * rstd * g[2 * t + 1] + be[2 * t + 1];
  unsigned int pk = (unsigned int)f2bf(o0) | ((unsigned int)f2bf(o1) << 16);
  *(unsigned int*)(out + (size_t)row * 512 + 2 * t) = pk;
}

// ------------- weight transpose+convert: in [K][N] f32 -> out [N][K] bf16 ---
__global__ __launch_bounds__(256) void wtrans(const float* __restrict__ in,
                                              ushort_t* __restrict__ outw,
                                              int K, int N) {
  __shared__ float tile[64][65];
  int kb = blockIdx.x * 64, nb = blockIdx.y * 64, t = threadIdx.x;
  for (int i = t; i < 4096; i += 256) {
    int r = i >> 6, c = i & 63;
    tile[r][c] = in[(size_t)(kb + r) * N + nb + c];
  }
  __syncthreads();
  for (int i = t; i < 4096; i += 256) {
    int r = i >> 6, c = i & 63;
    outw[(size_t)(nb + r) * K + kb + c] = f2bf(tile[c][r]);
  }
}

// ------------- MFMA GEMM: [32768,512](bf16) @ Wt[1536,512]^T -> q/k/vT ------
// grid (256, 12); 2-phase dbuf staging; scattered epilogue (proven form).
__global__ __launch_bounds__(256) void gemm_qkv_mfma(const short* __restrict__ Abf,
                                                     const short* __restrict__ Wt,
                                                     ushort_t* __restrict__ q,
                                                     ushort_t* __restrict__ k,
                                                     ushort_t* __restrict__ vT) {
  int bm0 = blockIdx.x * 128, bn0 = blockIdx.y * 128;
  __shared__ __align__(16) short As[2 * 4096];
  __shared__ __align__(16) short Bs[2 * 4096];
  int t = threadIdx.x, l = t & 63, w = t >> 6;
  int wr = w >> 1, wc = w & 1;
  int arow = w * 32 + (l >> 2);
  int akoff = (l & 3) * 8;
  const short* ag = Abf + (size_t)(bm0 + arow) * 512 + akoff;
  const short* bg = Wt + (size_t)(bn0 + arow) * 512 + akoff;
  int lr = l & 15, lk = (l >> 4) * 8;

  auto stage = [&](int k0, int d) {
    short* Adst = As + d * 4096 + w * 1024;
    short* Bdst = Bs + d * 4096 + w * 1024;
    __builtin_amdgcn_global_load_lds(GPTR(ag + k0), LPTR(Adst), 16, 0, 0);
    __builtin_amdgcn_global_load_lds(GPTR(ag + k0 + 16 * 512), LPTR(Adst + 512), 16, 0, 0);
    __builtin_amdgcn_global_load_lds(GPTR(bg + k0), LPTR(Bdst), 16, 0, 0);
    __builtin_amdgcn_global_load_lds(GPTR(bg + k0 + 16 * 512), LPTR(Bdst + 512), 16, 0, 0);
  };

  f32x4 acc[16];
#pragma unroll
  for (int i = 0; i < 16; i++) acc[i] = (f32x4){0.f, 0.f, 0.f, 0.f};

  stage(0, 0);
  __syncthreads();
  for (int s = 0; s < 16; s++) {
    if (s < 15) stage((s + 1) * 32, (s + 1) & 1);
    const short* Ard = As + (s & 1) * 4096 + (wr * 64 + lr) * 32 + lk;
    const short* Brd = Bs + (s & 1) * 4096 + (wc * 64 + lr) * 32 + lk;
    short8 af[4], bf[4];
#pragma unroll
    for (int mf = 0; mf < 4; mf++) af[mf] = *(const short8*)(Ard + mf * 512);
#pragma unroll
    for (int nf = 0; nf < 4; nf++) bf[nf] = *(const short8*)(Brd + nf * 512);
#pragma unroll
    for (int mf = 0; mf < 4; mf++)
#pragma unroll
      for (int nf = 0; nf < 4; nf++)
        acc[mf * 4 + nf] = __builtin_amdgcn_mfma_f32_16x16x32_bf16(af[mf], bf[nf], acc[mf * 4 + nf], 0, 0, 0);
    __syncthreads();
  }
#pragma unroll
  for (int mf = 0; mf < 4; mf++)
#pragma unroll
    for (int nf = 0; nf < 4; nf++) {
      int gn = bn0 + wc * 64 + nf * 16 + (l & 15);
      int part = gn >> 9, head = (gn >> 6) & 7, d = gn & 63;
      int rbase = bm0 + wr * 64 + mf * 16 + ((l >> 4) << 2);
      int bhead = (rbase >> 13) * 8 + head;
      if (part == 2) {
        union { ushort_t s[4]; unsigned long long u; } p4;
#pragma unroll
        for (int i = 0; i < 4; i++) p4.s[i] = f2bf(acc[mf * 4 + nf][i]);
        *(unsigned long long*)(vT + ((size_t)bhead * 64 + d) * 8192 + (rbase & 8191)) = p4.u;
      } else {
#pragma unroll
        for (int i = 0; i < 4; i++) {
          int gm = rbase + i;
          size_t dst = ((size_t)bhead * 8192 + (gm & 8191)) * 64 + d;
          float val = acc[mf * 4 + nf][i];
          if (part == 0) q[dst] = f2bf(val * 0.125f);
          else k[dst] = f2bf(val);
        }
      }
    }
}

// ------------- MFMA GEMM: gather(outh)[32768,512] @ Woutt^T + x + b -> out --
// grid (4, 256); single-buffered (measured-good form).
__global__ __launch_bounds__(256) void gemm_out_mfma(const ushort_t* __restrict__ outh,
                                                     const short* __restrict__ Wt,
                                                     const float* __restrict__ x,
                                                     const float* __restrict__ bo,
                                                     float* __restrict__ out) {
  int bn0 = blockIdx.x * 128, bm0 = blockIdx.y * 128;
  __shared__ __align__(16) short As[128 * 32];
  __shared__ __align__(16) short Bs[128 * 32];
  int t = threadIdx.x, l = t & 63, w = t >> 6;
  int wr = w >> 1, wc = w & 1;
  int arow = w * 32 + (l >> 2);
  int akoff = (l & 3) * 8;
  int gm0 = bm0 + arow, gm1 = gm0 + 16;
  const short* bg = Wt + (size_t)(bn0 + arow) * 512 + akoff;
  short* Adst = As + w * 1024;
  short* Bdst = Bs + w * 1024;
  int lr = l & 15, lk = (l >> 4) * 8;
  const short* Ard = As + (wr * 64 + lr) * 32 + lk;
  const short* Brd = Bs + (wc * 64 + lr) * 32 + lk;
  f32x4 acc[16];
#pragma unroll
  for (int i = 0; i < 16; i++) acc[i] = (f32x4){0.f, 0.f, 0.f, 0.f};
  for (int k0 = 0; k0 < 512; k0 += 32) {
    int kk = k0 + akoff;
    const ushort_t* a0 = outh + ((size_t)((gm0 >> 13) * 8 + (kk >> 6)) * 8192 + (gm0 & 8191)) * 64 + (kk & 63);
    const ushort_t* a1 = outh + ((size_t)((gm1 >> 13) * 8 + (kk >> 6)) * 8192 + (gm1 & 8191)) * 64 + (kk & 63);
    __builtin_amdgcn_global_load_lds(GPTR(a0), LPTR(Adst), 16, 0, 0);
    __builtin_amdgcn_global_load_lds(GPTR(a1), LPTR(Adst + 512), 16, 0, 0);
    __builtin_amdgcn_global_load_lds(GPTR(bg + k0), LPTR(Bdst), 16, 0, 0);
    __builtin_amdgcn_global_load_lds(GPTR(bg + k0 + 16 * 512), LPTR(Bdst + 512), 16, 0, 0);
    __syncthreads();
    short8 af[4], bf[4];
#pragma unroll
    for (int mf = 0; mf < 4; mf++) af[mf] = *(const short8*)(Ard + mf * 512);
#pragma unroll
    for (int nf = 0; nf < 4; nf++) bf[nf] = *(const short8*)(Brd + nf * 512);
#pragma unroll
    for (int mf = 0; mf < 4; mf++)
#pragma unroll
      for (int nf = 0; nf < 4; nf++)
        acc[mf * 4 + nf] = __builtin_amdgcn_mfma_f32_16x16x32_bf16(af[mf], bf[nf], acc[mf * 4 + nf], 0, 0, 0);
    __syncthreads();
  }
#pragma unroll
  for (int mf = 0; mf < 4; mf++)
#pragma unroll
    for (int nf = 0; nf < 4; nf++) {
      int gn = bn0 + wc * 64 + nf * 16 + (l & 15);
      int rbase = bm0 + wr * 64 + mf * 16 + ((l >> 4) << 2);
#pragma unroll
      for (int i = 0; i < 4; i++) {
        int gm = rbase + i;
        size_t o = (size_t)gm * 512 + gn;
        out[o] = x[o] + bo[gn] + acc[mf * 4 + nf][i];
      }
    }
}

// --------- landmarks: mean over 32 rows (vectorized; 1 wave per mi) ---------
__global__ __launch_bounds__(256) void land_kernel(const ushort_t* __restrict__ q,
                                                   const ushort_t* __restrict__ k,
                                                   float* __restrict__ qlf,
                                                   float* __restrict__ klf,
                                                   ushort_t* __restrict__ qlh,
                                                   ushort_t* __restrict__ klh) {
  int bh = blockIdx.y;
  int wv = threadIdx.x >> 6, l = threadIdx.x & 63;
  int mi = blockIdx.x * 4 + wv;
  size_t base = ((size_t)bh * 8192 + (size_t)mi * 32) * 64;
  float sq[8], sk[8];
#pragma unroll
  for (int e = 0; e < 8; e++) { sq[e] = 0.f; sk[e] = 0.f; }
#pragma unroll
  for (int j = 0; j < 4; j++) {
    uint4 uq = *(const uint4*)(q + base + (size_t)(j * 64 + l) * 8);
    uint4 uk = *(const uint4*)(k + base + (size_t)(j * 64 + l) * 8);
    const ushort_t* aq = (const ushort_t*)&uq;
    const ushort_t* ak = (const ushort_t*)&uk;
#pragma unroll
    for (int e = 0; e < 8; e++) { sq[e] += bf2f(aq[e]); sk[e] += bf2f(ak[e]); }
  }
#pragma unroll
  for (int m = 8; m < 64; m <<= 1)
#pragma unroll
    for (int e = 0; e < 8; e++) { sq[e] += __shfl_xor(sq[e], m); sk[e] += __shfl_xor(sk[e], m); }
  if (l < 8) {
    size_t o = ((size_t)bh * 256 + mi) * 64 + l * 8;
    union { ushort_t s[8]; uint4 u; } hq, hk;
#pragma unroll
    for (int e = 0; e < 8; e++) {
      float aq2 = sq[e] * (1.f / 32.f), ak2 = sk[e] * (1.f / 32.f);
      qlf[o + e] = aq2; klf[o + e] = ak2;
      hq.s[e] = f2bf(aq2); hk.s[e] = f2bf(ak2);
    }
    *(uint4*)(qlh + o) = hq.u;
    *(uint4*)(klh + o) = hk.u;
  }
}

// --------- sim2 + softmax -> x (attn2) as hi/lo bf16 [32][256][256] ---------
__global__ __launch_bounds__(256) void sim2_kernel(const float* __restrict__ ql,
                                                   const float* __restrict__ kl,
                                                   ushort_t* __restrict__ xh,
                                                   ushort_t* __restrict__ xl) {
  int bh = blockIdx.y, row = blockIdx.x, t = threadIdx.x;
  __shared__ float qrow[64];
  __shared__ float red[256];
  if (t < 64) qrow[t] = ql[((size_t)bh * 256 + row) * 64 + t];
  __syncthreads();
  const float* kr = kl + ((size_t)bh * 256 + t) * 64;
  float s = 0.f;
#pragma unroll
  for (int kd = 0; kd < 64; kd++) s = fmaf(qrow[kd], kr[kd], s);
  red[t] = s; __syncthreads();
  for (int off = 128; off > 0; off >>= 1) { if (t < off) red[t] = fmaxf(red[t], red[t + off]); __syncthreads(); }
  float mx = red[0]; __syncthreads();
  float pv = __expf(s - mx);
  red[t] = pv; __syncthreads();
  for (int off = 128; off > 0; off >>= 1) { if (t < off) red[t] += red[t + off]; __syncthreads(); }
  float pn = pv / red[0];
  size_t idx = ((size_t)bh << 16) + (size_t)row * 256 + t;
  ushort_t hi = f2bf(pn);
  xh[idx] = hi;
  xl[idx] = f2bf(pn - bf2f(hi));
}

// ------------- pinv init: abs row/col sums from hi/lo ----------------------
__global__ __launch_bounds__(256) void abssum_kernel(const ushort_t* __restrict__ xh,
                                                     const ushort_t* __restrict__ xl,
                                                     float* __restrict__ rowsum,
                                                     float* __restrict__ colsum) {
  int bh = blockIdx.x, t = threadIdx.x;
  size_t off = (size_t)bh << 16;
  float s = 0.f;
  for (int c = 0; c < 256; c++) {
    size_t i = off + (size_t)t * 256 + c;
    s += fabsf(bf2f(xh[i]) + bf2f(xl[i]));
  }
  rowsum[bh * 256 + t] = s;
  float s2 = 0.f;
  for (int r = 0; r < 256; r++) {
    size_t i = off + (size_t)r * 256 + t;
    s2 += fabsf(bf2f(xh[i]) + bf2f(xl[i]));
  }
  colsum[bh * 256 + t] = s2;
}

__global__ __launch_bounds__(256) void pinv_scale_kernel(const float* __restrict__ rowsum,
                                                         const float* __restrict__ colsum,
                                                         float* __restrict__ scl) {
  int t = threadIdx.x;
  float m1 = 0.f, m2 = 0.f;
  for (int i = t; i < 8192; i += 256) { m1 = fmaxf(m1, rowsum[i]); m2 = fmaxf(m2, colsum[i]); }
  __shared__ float r1[256], r2[256];
  r1[t] = m1; r2[t] = m2; __syncthreads();
  for (int off = 128; off > 0; off >>= 1) {
    if (t < off) { r1[t] = fmaxf(r1[t], r1[t + off]); r2[t] = fmaxf(r2[t], r2[t + off]); }
    __syncthreads();
  }
  if (t == 0) scl[0] = 1.f / (r1[0] * r2[0]);
}

// ------------- z0 = x^T*s (row hi/lo) and z0^T = x*s (hi/lo) ---------------
__global__ __launch_bounds__(256) void zinit_kernel(const ushort_t* __restrict__ xh,
                                                    const ushort_t* __restrict__ xl,
                                                    const float* __restrict__ scl,
                                                    ushort_t* __restrict__ zrh,
                                                    ushort_t* __restrict__ zrl,
                                                    ushort_t* __restrict__ zth,
                                                    ushort_t* __restrict__ ztl) {
  int bh = blockIdx.y, i = blockIdx.x, j = threadIdx.x;
  size_t off = (size_t)bh << 16;
  float s = scl[0];
  size_t src1 = off + (size_t)j * 256 + i;
  float v1 = (bf2f(xh[src1]) + bf2f(xl[src1])) * s;
  size_t dst = off + (size_t)i * 256 + j;
  ushort_t h1 = f2bf(v1);
  zrh[dst] = h1; zrl[dst] = f2bf(v1 - bf2f(h1));
  size_t src2 = off + (size_t)i * 256 + j;
  float v2 = (bf2f(xh[src2]) + bf2f(xl[src2])) * s;
  ushort_t h2 = f2bf(v2);
  zth[dst] = h2; ztl[dst] = f2bf(v2 - bf2f(h2));
}

// ------- NS split-precision MFMA GEMM on [32][256][256] hi/lo bf16 ---------
// MODE 0: E=acc;          write C rows + C^T     (A = x@z)
// MODE 1: E=acc-7Ex+15I;  write C^T only         (D = A@A-7A+15I)
// MODE 2: E=13I-acc;      write C^T only         (B3 = 13I-A@D)
// MODE 3: E=0.25*acc;     write C rows + C^T     (z' = 0.25*z@B3)
// FULL=1: hi/lo 3-MFMA split; FULL=0: bf16-only. WRLO=1: store lo arrays.
template<int MODE, int FULL, int WRLO>
__global__ __launch_bounds__(256) void bmm_ns(
    const ushort_t* __restrict__ Agh, const ushort_t* __restrict__ Agl,
    const ushort_t* __restrict__ Bgh, const ushort_t* __restrict__ Bgl,
    const ushort_t* __restrict__ Exh, const ushort_t* __restrict__ Exl,
    ushort_t* __restrict__ C1h, ushort_t* __restrict__ C1l,
    ushort_t* __restrict__ C2h, ushort_t* __restrict__ C2l) {
  __shared__ __align__(16) char smem[FULL ? 65536 : 32768];
  char* AhB = smem;
  char* BhB = smem + 16384;
  char* AlB = smem + 32768;   // only touched when FULL
  char* BlB = smem + 49152;

  int t = threadIdx.x, l = t & 63, w = t >> 6, h = l >> 5;
  int tile = blockIdx.x, bh = blockIdx.y;
  int tr = (tile >> 2) << 6, tc = (tile & 3) << 6;
  size_t off = (size_t)bh << 16;

  int id0 = w * 64 + l, id1 = id0 + 256;
  int r0 = id0 >> 3, cs0 = (id0 & 7) ^ (r0 & 7);
  int r1 = id1 >> 3, cs1 = (id1 & 7) ^ (r1 & 7);

  auto stage = [&](int s, int d) {
    int k0 = s << 6;
    int db = d * 8192;
    __builtin_amdgcn_global_load_lds(GPTR(Agh + off + (size_t)(tr + r0) * 256 + k0 + cs0 * 8), LPTR(AhB + db + w * 1024), 16, 0, 0);
    __builtin_amdgcn_global_load_lds(GPTR(Agh + off + (size_t)(tr + r1) * 256 + k0 + cs1 * 8), LPTR(AhB + db + w * 1024 + 4096), 16, 0, 0);
    __builtin_amdgcn_global_load_lds(GPTR(Bgh + off + (size_t)(tc + r0) * 256 + k0 + cs0 * 8), LPTR(BhB + db + w * 1024), 16, 0, 0);
    __builtin_amdgcn_global_load_lds(GPTR(Bgh + off + (size_t)(tc + r1) * 256 + k0 + cs1 * 8), LPTR(BhB + db + w * 1024 + 4096), 16, 0, 0);
    if (FULL) {
      __builtin_amdgcn_global_load_lds(GPTR(Agl + off + (size_t)(tr + r0) * 256 + k0 + cs0 * 8), LPTR(AlB + db + w * 1024), 16, 0, 0);
      __builtin_amdgcn_global_load_lds(GPTR(Agl + off + (size_t)(tr + r1) * 256 + k0 + cs1 * 8), LPTR(AlB + db + w * 1024 + 4096), 16, 0, 0);
      __builtin_amdgcn_global_load_lds(GPTR(Bgl + off + (size_t)(tc + r0) * 256 + k0 + cs0 * 8), LPTR(BlB + db + w * 1024), 16, 0, 0);
      __builtin_amdgcn_global_load_lds(GPTR(Bgl + off + (size_t)(tc + r1) * 256 + k0 + cs1 * 8), LPTR(BlB + db + w * 1024 + 4096), 16, 0, 0);
    }
  };

  f32x16 acc;
#pragma unroll
  for (int i = 0; i < 16; i++) acc[i] = 0.f;

  int rA = ((w >> 1) << 5) + (l & 31);
  int rB = ((w & 1) << 5) + (l & 31);
  int baA = rA << 7, baB = rB << 7;

  stage(0, 0);
  __syncthreads();
  for (int s = 0; s < 4; s++) {
    if (s < 3) stage(s + 1, (s + 1) & 1);
    int db = (s & 1) * 8192;
#pragma unroll
    for (int kk = 0; kk < 4; kk++) {
      int swA = (((kk << 1) + h) ^ (rA & 7)) << 4;
      int swB = (((kk << 1) + h) ^ (rB & 7)) << 4;
      short8 afh = *(const short8*)(AhB + db + baA + swA);
      short8 bfh = *(const short8*)(BhB + db + baB + swB);
      acc = __builtin_amdgcn_mfma_f32_32x32x16_bf16(afh, bfh, acc, 0, 0, 0);
      if (FULL) {
        short8 afl = *(const short8*)(AlB + db + baA + swA);
        short8 bfl = *(const short8*)(BlB + db + baB + swB);
        acc = __builtin_amdgcn_mfma_f32_32x32x16_bf16(afh, bfl, acc, 0, 0, 0);
        acc = __builtin_amdgcn_mfma_f32_32x32x16_bf16(afl, bfh, acc, 0, 0, 0);
      }
    }
    __syncthreads();
  }

  int qr = tr + ((w >> 1) << 5);
  int nloc = ((w & 1) << 5) + (l & 31);
  int gn = tc + nloc;
  ushort_t his[16], los[16];
  int ms[16];
#pragma unroll
  for (int reg = 0; reg < 16; reg++) {
    int m = (reg & 3) + ((reg >> 2) << 3) + (h << 2);
    int gm = qr + m;
    float e = acc[reg];
    if (MODE == 1) {
      size_t ei = off + (size_t)gm * 256 + gn;
      float ex = bf2f(Exh[ei]);
      if (FULL) ex += bf2f(Exl[ei]);   // cheap path: hi only (lo may be stale)
      e = e - 7.f * ex + (gm == gn ? 15.f : 0.f);
    } else if (MODE == 2) {
      e = (gm == gn ? 13.f : 0.f) - e;
    } else if (MODE == 3) {
      e *= 0.25f;
    }
    his[reg] = f2bf(e);
    if (WRLO) los[reg] = f2bf(e - bf2f(his[reg]));
    ms[reg] = ((w >> 1) << 5) + m;
  }
  ushort_t* Whi = (ushort_t*)smem;
  ushort_t* Wlo = ((ushort_t*)smem) + 4608;
#pragma unroll
  for (int reg = 0; reg < 16; reg++) {
    Whi[nloc * 72 + ms[reg]] = his[reg];
    if (WRLO) Wlo[nloc * 72 + ms[reg]] = los[reg];
  }
  __syncthreads();
  {
    int rr = t >> 2, seg = (t & 3) << 4;
    uint4 h0 = *(const uint4*)(Whi + rr * 72 + seg);
    uint4 h1 = *(const uint4*)(Whi + rr * 72 + seg + 8);
    size_t d2 = off + (size_t)(tc + rr) * 256 + tr + seg;
    *(uint4*)(C2h + d2) = h0; *(uint4*)(C2h + d2 + 8) = h1;
    if (WRLO) {
      uint4 l0 = *(const uint4*)(Wlo + rr * 72 + seg);
      uint4 l1 = *(const uint4*)(Wlo + rr * 72 + seg + 8);
      *(uint4*)(C2l + d2) = l0; *(uint4*)(C2l + d2 + 8) = l1;
    }
  }
  if (MODE == 0 || MODE == 3) {
    __syncthreads();
#pragma unroll
    for (int reg = 0; reg < 16; reg++) {
      Whi[ms[reg] * 72 + nloc] = his[reg];
      if (WRLO) Wlo[ms[reg] * 72 + nloc] = los[reg];
    }
    __syncthreads();
    int rr = t >> 2, seg = (t & 3) << 4;
    uint4 h0 = *(const uint4*)(Whi + rr * 72 + seg);
    uint4 h1 = *(const uint4*)(Whi + rr * 72 + seg + 8);
    size_t d1 = off + (size_t)(tr + rr) * 256 + tc + seg;
    *(uint4*)(C1h + d1) = h0; *(uint4*)(C1h + d1 + 8) = h1;
    if (WRLO) {
      uint4 l0 = *(const uint4*)(Wlo + rr * 72 + seg);
      uint4 l1 = *(const uint4*)(Wlo + rr * 72 + seg + 8);
      *(uint4*)(C1l + d1) = l0; *(uint4*)(C1l + d1 + 8) = l1;
    }
  }
}

// ------------- MFMA flash: out = softmax(qsrc @ ksrc^T) @ V ----------------
// write_partial=0 additionally fuses the depthwise conv residual from convsrc
// (vT layout [bh][64][8192]) into the output store.
__global__ __launch_bounds__(256) void flash_mfma(
    const ushort_t* __restrict__ qsrc, const ushort_t* __restrict__ ksrc,
    const ushort_t* __restrict__ vts, ushort_t* __restrict__ outb,
    float* __restrict__ pOT, float* __restrict__ pM, float* __restrict__ pL,
    const ushort_t* __restrict__ convsrc, const float* __restrict__ wcv,
    int nq, int nkv, int vt_stride, int nsplit, int write_partial) {
  __shared__ __align__(16) char smem[38400];
  ushort_t* Ks = (ushort_t*)smem;
  ushort_t* Vs = (ushort_t*)(smem + 8192);

  int t = threadIdx.x, l = t & 63, w = t >> 6, h = l >> 5, ql = l & 31;
  int qtile = blockIdx.x, sp = blockIdx.y, bh = blockIdx.z;
  int chunk = nkv / nsplit;
  int kvbase = sp * chunk;
  int qg = qtile * 128 + w * 32 + ql;

  const ushort_t* qp = qsrc + ((size_t)bh * nq + qg) * 64;
  short8 qf[4];
#pragma unroll
  for (int kk = 0; kk < 4; kk++) qf[kk] = *(const short8*)(qp + kk * 16 + h * 8);

  f32x16 acc0, acc1;
#pragma unroll
  for (int i = 0; i < 16; i++) { acc0[i] = 0.f; acc1[i] = 0.f; }

  int c0 = w * 64 + l, c1 = c0 + 256;
  int r0 = c0 >> 3, s0 = ((c0 & 7) ^ (r0 & 7)) << 3;
  int r1 = c1 >> 3, s1 = ((c1 & 7) ^ (r1 & 7)) << 3;
  const ushort_t* kb = ksrc + (size_t)bh * nkv * 64;
  const ushort_t* vb = vts + (size_t)bh * 64 * vt_stride;

  float mrun = -1e30f, lrun = 0.f;
  int ntiles = chunk >> 6;
  for (int it = 0; it < ntiles; it++) {
    int kvt = kvbase + it * 64;
    __syncthreads();
    __builtin_amdgcn_global_load_lds(GPTR(kb + (size_t)(kvt + r0) * 64 + s0), LPTR(Ks + w * 512), 16, 0, 0);
    __builtin_amdgcn_global_load_lds(GPTR(kb + (size_t)(kvt + r1) * 64 + s1), LPTR(Ks + 2048 + w * 512), 16, 0, 0);
    __builtin_amdgcn_global_load_lds(GPTR(vb + (size_t)r0 * vt_stride + kvt + s0), LPTR(Vs + w * 512), 16, 0, 0);
    __builtin_amdgcn_global_load_lds(GPTR(vb + (size_t)r1 * vt_stride + kvt + s1), LPTR(Vs + 2048 + w * 512), 16, 0, 0);
    __syncthreads();

    f32x16 st0, st1;
#pragma unroll
    for (int i = 0; i < 16; i++) { st0[i] = 0.f; st1[i] = 0.f; }
#pragma unroll
    for (int kk = 0; kk < 4; kk++) {
      int ch = kk * 2 + h;
      short8 kf0 = *(const short8*)(Ks + ql * 64 + ((ch ^ (ql & 7)) << 3));
      short8 kf1 = *(const short8*)(Ks + (32 + ql) * 64 + ((ch ^ (ql & 7)) << 3));
      st0 = __builtin_amdgcn_mfma_f32_32x32x16_bf16(kf0, qf[kk], st0, 0, 0, 0);
      st1 = __builtin_amdgcn_mfma_f32_32x32x16_bf16(kf1, qf[kk], st1, 0, 0, 0);
    }

    float tm = -1e30f;
#pragma unroll
    for (int r2 = 0; r2 < 16; r2++) { tm = fmaxf(tm, st0[r2]); tm = fmaxf(tm, st1[r2]); }
    tm = fmaxf(tm, __shfl_xor(tm, 32));
    float mnew = fmaxf(mrun, tm);
    float scal = __expf(mrun - mnew);
    float tsum = 0.f;
#pragma unroll
    for (int r2 = 0; r2 < 16; r2++) {
      float p0 = __expf(st0[r2] - mnew); st0[r2] = p0; tsum += p0;
      float p1 = __expf(st1[r2] - mnew); st1[r2] = p1; tsum += p1;
    }
    tsum += __shfl_xor(tsum, 32);
    lrun = lrun * scal + tsum;
    mrun = mnew;
#pragma unroll
    for (int r2 = 0; r2 < 16; r2++) { acc0[r2] *= scal; acc1[r2] *= scal; }

#pragma unroll
    for (int nf = 0; nf < 2; nf++) {
      f32x16 stv = (nf == 0) ? st0 : st1;
      unsigned int pk[8], sw[8];
#pragma unroll
      for (int g2 = 0; g2 < 4; g2++) {
        pk[g2 * 2]     = (unsigned int)f2bf(stv[g2 * 4])     | ((unsigned int)f2bf(stv[g2 * 4 + 1]) << 16);
        pk[g2 * 2 + 1] = (unsigned int)f2bf(stv[g2 * 4 + 2]) | ((unsigned int)f2bf(stv[g2 * 4 + 3]) << 16);
      }
#pragma unroll
      for (int i2 = 0; i2 < 8; i2++) sw[i2] = (unsigned int)__shfl_xor((int)pk[i2], 32);
      union { unsigned int u[4]; short8 s; } bfr0, bfr1;
      if (h == 0) {
        bfr0.u[0] = pk[0]; bfr0.u[1] = pk[1]; bfr0.u[2] = sw[0]; bfr0.u[3] = sw[1];
        bfr1.u[0] = pk[4]; bfr1.u[1] = pk[5]; bfr1.u[2] = sw[4]; bfr1.u[3] = sw[5];
      } else {
        bfr0.u[0] = sw[2]; bfr0.u[1] = sw[3]; bfr0.u[2] = pk[2]; bfr0.u[3] = pk[3];
        bfr1.u[0] = sw[6]; bfr1.u[1] = sw[7]; bfr1.u[2] = pk[6]; bfr1.u[3] = pk[7];
      }
#pragma unroll
      for (int ks2 = 0; ks2 < 2; ks2++) {
        int ch2 = nf * 4 + ks2 * 2 + h;
        short8 vf0 = *(const short8*)(Vs + ql * 64 + ((ch2 ^ (ql & 7)) << 3));
        short8 vf1 = *(const short8*)(Vs + (32 + ql) * 64 + ((ch2 ^ (ql & 7)) << 3));
        short8 pf = ks2 ? bfr1.s : bfr0.s;
        acc0 = __builtin_amdgcn_mfma_f32_32x32x16_bf16(vf0, pf, acc0, 0, 0, 0);
        acc1 = __builtin_amdgcn_mfma_f32_32x32x16_bf16(vf1, pf, acc1, 0, 0, 0);
      }
    }
  }

  if (write_partial) {
    size_t ob = (size_t)bh * nsplit + sp;
#pragma unroll
    for (int r2 = 0; r2 < 16; r2++) {
      int row = (r2 & 3) + 8 * (r2 >> 2) + 4 * h;
      pOT[(ob * 64 + row) * nq + qg] = acc0[r2];
      pOT[(ob * 64 + 32 + row) * nq + qg] = acc1[r2];
    }
    if (h == 0) { pM[ob * nq + qg] = mrun; pL[ob * nq + qg] = lrun; }
  } else {
    // ---- fused epilogue: attn/l -> Ot (bf16), conv window -> vsb, combine ---
    float inv = 1.f / lrun;
    __syncthreads();
    ushort_t* Otb = (ushort_t*)smem;             // [64][136] bf16 (17408 B)
    ushort_t* vsb = (ushort_t*)(smem + 17408);   // [64][164] bf16 (20992 B)
#pragma unroll
    for (int r2 = 0; r2 < 16; r2++) {
      int row = (r2 & 3) + 8 * (r2 >> 2) + 4 * h;
      Otb[row * 136 + w * 32 + ql] = f2bf(acc0[r2] * inv);
      Otb[(32 + row) * 136 + w * 32 + ql] = f2bf(acc1[r2] * inv);
    }
    {
      int r = t >> 2, part = t & 3;
      const ushort_t* src = convsrc + ((size_t)bh * 64 + r) * 8192;
      int n0 = qtile * 128;
#pragma unroll
      for (int j = 0; j < 5; j++) {
        int col = part * 40 + j * 8;
        int gn = n0 - 16 + col;
        if (gn >= 0 && gn + 7 < 8192) {
          *(uint2*)&vsb[r * 164 + col] = *(const uint2*)(src + gn);
          *(uint2*)&vsb[r * 164 + col + 4] = *(const uint2*)(src + gn + 4);
        } else {
#pragma unroll
          for (int e = 0; e < 8; e++) {
            int g2 = gn + e;
            vsb[r * 164 + col + e] = (g2 >= 0 && g2 < 8192) ? src[g2] : (ushort_t)0;
          }
        }
      }
    }
    __syncthreads();
    int d = t & 63, ng = t >> 6;
    float win[64];
#pragma unroll
    for (int j2 = 0; j2 < 16; j2++) {
      uint2 u = *(const uint2*)&vsb[d * 164 + ng * 32 + j2 * 4];
      const ushort_t* us = (const ushort_t*)&u;
      win[j2 * 4 + 0] = bf2f(us[0]); win[j2 * 4 + 1] = bf2f(us[1]);
      win[j2 * 4 + 2] = bf2f(us[2]); win[j2 * 4 + 3] = bf2f(us[3]);
    }
    int hh = bh & 7;
    float o[32];
#pragma unroll
    for (int i = 0; i < 32; i++) o[i] = 0.f;
#pragma unroll
    for (int kk = 0; kk < 33; kk++) {
      float wv = wcv[hh * 33 + kk];
#pragma unroll
      for (int i = 0; i < 32; i++) o[i] = fmaf(wv, win[i + kk], o[i]);
    }
    ushort_t* op = outb + ((size_t)bh * nq + qtile * 128 + ng * 32) * 64 + d;
#pragma unroll
    for (int i = 0; i < 32; i++) {
      float attn = bf2f(Otb[d * 136 + ng * 32 + i]);
      op[(size_t)i * 64] = f2bf(attn + o[i]);
    }
  }
}

// ------------- combine split-KV partials -> T bf16 [bh][256][64] -----------
#define NSPLIT 16
__global__ __launch_bounds__(256) void flash_combine(const float* __restrict__ pOT,
                                                     const float* __restrict__ pM,
                                                     const float* __restrict__ pL,
                                                     ushort_t* __restrict__ T, int nq) {
  int bh = blockIdx.x, qq = threadIdx.x;
  float ms[NSPLIT], ww[NSPLIT];
  float M = -1e30f;
#pragma unroll
  for (int s = 0; s < NSPLIT; s++) {
    ms[s] = pM[((size_t)bh * NSPLIT + s) * nq + qq];
    M = fmaxf(M, ms[s]);
  }
  float L = 0.f;
#pragma unroll
  for (int s = 0; s < NSPLIT; s++) {
    ww[s] = __expf(ms[s] - M);
    L += ww[s] * pL[((size_t)bh * NSPLIT + s) * nq + qq];
  }
  float invL = 1.f / L;
  ushort_t* tp = T + ((size_t)bh * nq + qq) * 64;
  for (int d0 = 0; d0 < 64; d0 += 8) {
    union { ushort_t s[8]; uint4 u; } o8;
#pragma unroll
    for (int j = 0; j < 8; j++) {
      int d = d0 + j;
      float o = 0.f;
#pragma unroll
      for (int s = 0; s < NSPLIT; s++)
        o += ww[s] * pOT[(((size_t)bh * NSPLIT + s) * 64 + d) * nq + qq];
      o8.s[j] = f2bf(o * invL);
    }
    *(uint4*)(tp + d0) = o8.u;
  }
}

// ------------- U^T = (z @ T)^T : UT[bh][64][256], z from hi/lo --------------
__global__ __launch_bounds__(256) void zu_kernel(const ushort_t* __restrict__ zh,
                                                 const ushort_t* __restrict__ zl,
                                                 const ushort_t* __restrict__ T,
                                                 ushort_t* __restrict__ UT) {
  __shared__ __align__(16) ushort_t Ts[16384];   // [256][64]
  __shared__ __align__(16) ushort_t Ub[64 * 40];
  int bh = blockIdx.y, r0 = blockIdx.x * 32, t = threadIdx.x;
  {
    const uint4* src = (const uint4*)(T + ((size_t)bh << 14));
    uint4* dst = (uint4*)Ts;
    for (int i = t; i < 2048; i += 256) dst[i] = src[i];
  }
  __syncthreads();
  int rloc = t >> 3, dseg = (t & 7) << 3;
  size_t zoff = ((size_t)bh << 16) + (size_t)(r0 + rloc) * 256;
  float acc[8];
#pragma unroll
  for (int j = 0; j < 8; j++) acc[j] = 0.f;
  for (int c0 = 0; c0 < 256; c0 += 8) {
    uint4 zhv = *(const uint4*)(zh + zoff + c0);
    uint4 zlv = *(const uint4*)(zl + zoff + c0);
    const ushort_t* z8h = (const ushort_t*)&zhv;
    const ushort_t* z8l = (const ushort_t*)&zlv;
#pragma unroll
    for (int cc = 0; cc < 8; cc++) {
      float zv = bf2f(z8h[cc]) + bf2f(z8l[cc]);
      short8 tv = *(const short8*)(Ts + (c0 + cc) * 64 + dseg);
#pragma unroll
      for (int j = 0; j < 8; j++) acc[j] = fmaf(zv, bf2f((ushort_t)tv[j]), acc[j]);
    }
  }
#pragma unroll
  for (int j = 0; j < 8; j++) Ub[(dseg + j) * 40 + rloc] = f2bf(acc[j]);
  __syncthreads();
  int d = t >> 2, rseg = (t & 3) << 3;
  uint4 v = *(const uint4*)(Ub + d * 40 + rseg);
  *(uint4*)(UT + ((size_t)bh * 64 + d) * 256 + r0 + rseg) = v;
}

extern "C" void kernel_launch(void* const* d_in, const int* in_sizes, int n_in,
                              void* d_out, int out_size, void* d_ws, size_t ws_size,
                              hipStream_t stream) {
  (void)in_sizes; (void)n_in; (void)out_size; (void)ws_size;
  const float* x     = (const float*)d_in[0];
  const float* g     = (const float*)d_in[1];
  const float* be    = (const float*)d_in[2];
  const float* wqkv  = (const float*)d_in[3];
  const float* wout  = (const float*)d_in[4];
  const float* bout  = (const float*)d_in[5];
  const float* convw = (const float*)d_in[6];
  float* out = (float*)d_out;

  char* base = (char*)d_ws;
  size_t off = 0;
  auto alloc = [&](size_t bytes) -> void* {
    void* r = base + off; off = (off + bytes + 255) & ~(size_t)255; return r;
  };
  const size_t NBH = (size_t)32 * 8192 * 64;
  const size_t M2 = (size_t)32 * 256 * 256 * 2;  // one [32][256][256] bf16 = 4 MB
  ushort_t* q     = (ushort_t*)alloc(NBH * 2);
  ushort_t* k     = (ushort_t*)alloc(NBH * 2);
  ushort_t* vT    = (ushort_t*)alloc(NBH * 2);
  ushort_t* outh  = (ushort_t*)alloc(NBH * 2);
  float*    qlf   = (float*)alloc((size_t)32 * 256 * 64 * 4);
  float*    klf   = (float*)alloc((size_t)32 * 256 * 64 * 4);
  ushort_t* qlh   = (ushort_t*)alloc((size_t)32 * 256 * 64 * 2);
  ushort_t* klh   = (ushort_t*)alloc((size_t)32 * 256 * 64 * 2);
  ushort_t* xh    = (ushort_t*)alloc(M2);
  ushort_t* xl    = (ushort_t*)alloc(M2);
  ushort_t* zArh  = (ushort_t*)alloc(M2);
  ushort_t* zArl  = (ushort_t*)alloc(M2);
  ushort_t* zAth  = (ushort_t*)alloc(M2);
  ushort_t* zAtl  = (ushort_t*)alloc(M2);
  ushort_t* zBrh  = (ushort_t*)alloc(M2);
  ushort_t* zBrl  = (ushort_t*)alloc(M2);
  ushort_t* zBth  = (ushort_t*)alloc(M2);
  ushort_t* zBtl  = (ushort_t*)alloc(M2);
  ushort_t* ARh   = (ushort_t*)alloc(M2);
  ushort_t* ARl   = (ushort_t*)alloc(M2);
  ushort_t* ATh   = (ushort_t*)alloc(M2);
  ushort_t* ATl   = (ushort_t*)alloc(M2);
  ushort_t* DTh   = (ushort_t*)alloc(M2);
  ushort_t* DTl   = (ushort_t*)alloc(M2);
  ushort_t* FTh   = (ushort_t*)alloc(M2);
  ushort_t* FTl   = (ushort_t*)alloc(M2);
  float*    rowsum = (float*)alloc(8192 * 4);
  float*    colsum = (float*)alloc(8192 * 4);
  float*    scl   = (float*)alloc(64);
  ushort_t* T     = (ushort_t*)alloc((size_t)32 * 256 * 64 * 2);
  ushort_t* UT    = (ushort_t*)alloc((size_t)32 * 64 * 256 * 2);
  ushort_t* Wqkvt = (ushort_t*)alloc((size_t)1536 * 512 * 2);
  ushort_t* Woutt = (ushort_t*)alloc((size_t)512 * 512 * 2);
  // Aliases: LN output Abf (33.55 MB) spans xh..zBtl (10 x 4.19 MB, written
  // only later). Flash partials (nsplit=16): pOT spans ARh..FTl (8 x 4.19 MB
  // = 33.55 MB exactly); pM/pL -> zBth/zBtl (iter-4 z ping-pong, dead after
  // the NS loop). All dead regions at flash time.
  short* Abf = (short*)xh;
  float* pOT = (float*)ARh;
  float* pM  = (float*)zBth;
  float* pL  = (float*)zBtl;

  ln_bf16<<<32768, 256, 0, stream>>>(x, g, be, (ushort_t*)Abf);
  wtrans<<<dim3(8, 24), 256, 0, stream>>>(wqkv, Wqkvt, 512, 1536);
  wtrans<<<dim3(8, 8), 256, 0, stream>>>(wout, Woutt, 512, 512);
  gemm_qkv_mfma<<<dim3(256, 12), 256, 0, stream>>>(Abf, (const short*)Wqkvt, q, k, vT);
  land_kernel<<<dim3(64, 32), 256, 0, stream>>>(q, k, qlf, klf, qlh, klh);
  sim2_kernel<<<dim3(256, 32), 256, 0, stream>>>(qlf, klf, xh, xl);
  abssum_kernel<<<32, 256, 0, stream>>>(xh, xl, rowsum, colsum);
  pinv_scale_kernel<<<1, 256, 0, stream>>>(rowsum, colsum, scl);
  zinit_kernel<<<dim3(256, 32), 256, 0, stream>>>(xh, xl, scl, zArh, zArl, zAth, zAtl);

  // NS loop (x-anchored; z self-corrects): iters 0-4 bf16-only, iter 5 hi/lo.
  ushort_t *zrh = zArh, *zrl = zArl, *zth = zAth, *ztl = zAtl;
  ushort_t *nrh = zBrh, *nrl = zBrl, *nth = zBth, *ntl = zBtl;
  dim3 nsgrid(16, 32);
  for (int it = 0; it < 6; it++) {
    if (it < 5) {
      bmm_ns<0, 0, 0><<<nsgrid, 256, 0, stream>>>(xh, xl, zth, ztl, xh, xl, ARh, ARl, ATh, ATl);
      bmm_ns<1, 0, 0><<<nsgrid, 256, 0, stream>>>(ARh, ARl, ATh, ATl, ARh, ARl, DTh, DTl, DTh, DTl);
      bmm_ns<2, 0, 0><<<nsgrid, 256, 0, stream>>>(ARh, ARl, DTh, DTl, xh, xl, FTh, FTl, FTh, FTl);
      if (it == 4)
        bmm_ns<3, 0, 1><<<nsgrid, 256, 0, stream>>>(zrh, zrl, FTh, FTl, xh, xl, nrh, nrl, nth, ntl);
      else
        bmm_ns<3, 0, 0><<<nsgrid, 256, 0, stream>>>(zrh, zrl, FTh, FTl, xh, xl, nrh, nrl, nth, ntl);
    } else {
      bmm_ns<0, 1, 1><<<nsgrid, 256, 0, stream>>>(xh, xl, zth, ztl, xh, xl, ARh, ARl, ATh, ATl);
      bmm_ns<1, 1, 1><<<nsgrid, 256, 0, stream>>>(ARh, ARl, ATh, ATl, ARh, ARl, DTh, DTl, DTh, DTl);
      bmm_ns<2, 1, 1><<<nsgrid, 256, 0, stream>>>(ARh, ARl, DTh, DTl, xh, xl, FTh, FTl, FTh, FTl);
      bmm_ns<3, 1, 1><<<nsgrid, 256, 0, stream>>>(zrh, zrl, FTh, FTl, xh, xl, nrh, nrl, nth, ntl);
    }
    std::swap(zrh, nrh); std::swap(zrl, nrl);
    std::swap(zth, nth); std::swap(ztl, ntl);
  }
  // after 6 swaps final z rows = zArh/zArl. AR/AT/DT/FT + zB* dead -> flash
  // scratch.

  // T = softmax(q_land @ k^T) @ v   (split-KV 16, partials f32)
  flash_mfma<<<dim3(2, 16, 32), 256, 0, stream>>>(qlh, k, vT, T, pOT, pM, pL,
                                                  vT, convw, 256, 8192, 8192, 16, 1);
  flash_combine<<<32, 256, 0, stream>>>(pOT, pM, pL, T, 256);
  // UT = (z @ T)^T
  zu_kernel<<<dim3(8, 32), 256, 0, stream>>>(zrh, zrl, T, UT);
  // outh = softmax(q @ k_land^T) @ U + depthwise conv residual (fused)
  flash_mfma<<<dim3(64, 1, 32), 256, 0, stream>>>(q, klh, UT, outh, pOT, pM, pL,
                                                  vT, convw, 8192, 256, 256, 1, 0);
  // d_out = x + concat_heads(outh) @ w_out + b_out
  gemm_out_mfma<<<dim3(4, 256), 256, 0, stream>>>(outh, (const short*)Woutt, x, bout, out);
}

// Round 15
// 595.443 us; speedup vs baseline: 1.2428x; 1.2428x over previous
//
#include <hip/hip_runtime.h>
#include <hip/hip_bf16.h>
#include <utility>

// Shapes: b=4, n=8192, d=512, h=8, dh=64, m=256 landmarks, l=32, conv k=33. bh=32.
// Round 15: flash_combine parallelized 32 -> 256 blocks (was 154us at 1.4%
// occupancy with NSPLIT=16; the m/l reduction is recomputed per d-slice).

typedef unsigned short ushort_t;
typedef __attribute__((ext_vector_type(8))) short short8;
typedef __attribute__((ext_vector_type(4))) float f32x4;
typedef __attribute__((ext_vector_type(16))) float f32x16;

#define GPTR(p) ((const __attribute__((address_space(1))) void*)(p))
#define LPTR(p) ((__attribute__((address_space(3))) void*)(p))

__device__ inline float bf2f(ushort_t u) {
  union { unsigned int i; float f; } x; x.i = ((unsigned int)u) << 16; return x.f;
}
__device__ inline ushort_t f2bf(float f) {
  union { float f; unsigned int i; } x; x.f = f;
  unsigned int r = x.i + 0x7FFF + ((x.i >> 16) & 1);   // round-nearest-even
  return (ushort_t)(r >> 16);
}

// ---------------- LayerNorm -> bf16 [32768][512] ----------------
__global__ __launch_bounds__(256) void ln_bf16(const float* __restrict__ x,
                                               const float* __restrict__ g,
                                               const float* __restrict__ be,
                                               ushort_t* __restrict__ out) {
  int row = blockIdx.x; int t = threadIdx.x;
  const float* xr = x + (size_t)row * 512;
  float2 v = *(const float2*)(xr + 2 * t);
  float s = v.x + v.y, qs = v.x * v.x + v.y * v.y;
#pragma unroll
  for (int o = 32; o > 0; o >>= 1) { s += __shfl_xor(s, o); qs += __shfl_xor(qs, o); }
  __shared__ float ps[4], pq[4];
  if ((t & 63) == 0) { ps[t >> 6] = s; pq[t >> 6] = qs; }
  __syncthreads();
  s = ps[0] + ps[1] + ps[2] + ps[3];
  qs = pq[0] + pq[1] + pq[2] + pq[3];
  float mu = s * (1.f / 512.f);
  float var = qs * (1.f / 512.f) - mu * mu;
  float rstd = rsqrtf(var + 1e-5f);
  float o0 = (v.x - mu) * rstd * g[2 * t] + be[2 * t];
  float o1 = (v.y - mu) * rstd * g[2 * t + 1] + be[2 * t + 1];
  unsigned int pk = (unsigned int)f2bf(o0) | ((unsigned int)f2bf(o1) << 16);
  *(unsigned int*)(out + (size_t)row * 512 + 2 * t) = pk;
}

// ------------- weight transpose+convert: in [K][N] f32 -> out [N][K] bf16 ---
__global__ __launch_bounds__(256) void wtrans(const float* __restrict__ in,
                                              ushort_t* __restrict__ outw,
                                              int K, int N) {
  __shared__ float tile[64][65];
  int kb = blockIdx.x * 64, nb = blockIdx.y * 64, t = threadIdx.x;
  for (int i = t; i < 4096; i += 256) {
    int r = i >> 6, c = i & 63;
    tile[r][c] = in[(size_t)(kb + r) * N + nb + c];
  }
  __syncthreads();
  for (int i = t; i < 4096; i += 256) {
    int r = i >> 6, c = i & 63;
    outw[(size_t)(nb + r) * K + kb + c] = f2bf(tile[c][r]);
  }
}

// ------------- MFMA GEMM: [32768,512](bf16) @ Wt[1536,512]^T -> q/k/vT ------
// grid (256, 12); 2-phase dbuf staging; scattered epilogue (proven form).
__global__ __launch_bounds__(256) void gemm_qkv_mfma(const short* __restrict__ Abf,
                                                     const short* __restrict__ Wt,
                                                     ushort_t* __restrict__ q,
                                                     ushort_t* __restrict__ k,
                                                     ushort_t* __restrict__ vT) {
  int bm0 = blockIdx.x * 128, bn0 = blockIdx.y * 128;
  __shared__ __align__(16) short As[2 * 4096];
  __shared__ __align__(16) short Bs[2 * 4096];
  int t = threadIdx.x, l = t & 63, w = t >> 6;
  int wr = w >> 1, wc = w & 1;
  int arow = w * 32 + (l >> 2);
  int akoff = (l & 3) * 8;
  const short* ag = Abf + (size_t)(bm0 + arow) * 512 + akoff;
  const short* bg = Wt + (size_t)(bn0 + arow) * 512 + akoff;
  int lr = l & 15, lk = (l >> 4) * 8;

  auto stage = [&](int k0, int d) {
    short* Adst = As + d * 4096 + w * 1024;
    short* Bdst = Bs + d * 4096 + w * 1024;
    __builtin_amdgcn_global_load_lds(GPTR(ag + k0), LPTR(Adst), 16, 0, 0);
    __builtin_amdgcn_global_load_lds(GPTR(ag + k0 + 16 * 512), LPTR(Adst + 512), 16, 0, 0);
    __builtin_amdgcn_global_load_lds(GPTR(bg + k0), LPTR(Bdst), 16, 0, 0);
    __builtin_amdgcn_global_load_lds(GPTR(bg + k0 + 16 * 512), LPTR(Bdst + 512), 16, 0, 0);
  };

  f32x4 acc[16];
#pragma unroll
  for (int i = 0; i < 16; i++) acc[i] = (f32x4){0.f, 0.f, 0.f, 0.f};

  stage(0, 0);
  __syncthreads();
  for (int s = 0; s < 16; s++) {
    if (s < 15) stage((s + 1) * 32, (s + 1) & 1);
    const short* Ard = As + (s & 1) * 4096 + (wr * 64 + lr) * 32 + lk;
    const short* Brd = Bs + (s & 1) * 4096 + (wc * 64 + lr) * 32 + lk;
    short8 af[4], bf[4];
#pragma unroll
    for (int mf = 0; mf < 4; mf++) af[mf] = *(const short8*)(Ard + mf * 512);
#pragma unroll
    for (int nf = 0; nf < 4; nf++) bf[nf] = *(const short8*)(Brd + nf * 512);
#pragma unroll
    for (int mf = 0; mf < 4; mf++)
#pragma unroll
      for (int nf = 0; nf < 4; nf++)
        acc[mf * 4 + nf] = __builtin_amdgcn_mfma_f32_16x16x32_bf16(af[mf], bf[nf], acc[mf * 4 + nf], 0, 0, 0);
    __syncthreads();
  }
#pragma unroll
  for (int mf = 0; mf < 4; mf++)
#pragma unroll
    for (int nf = 0; nf < 4; nf++) {
      int gn = bn0 + wc * 64 + nf * 16 + (l & 15);
      int part = gn >> 9, head = (gn >> 6) & 7, d = gn & 63;
      int rbase = bm0 + wr * 64 + mf * 16 + ((l >> 4) << 2);
      int bhead = (rbase >> 13) * 8 + head;
      if (part == 2) {
        union { ushort_t s[4]; unsigned long long u; } p4;
#pragma unroll
        for (int i = 0; i < 4; i++) p4.s[i] = f2bf(acc[mf * 4 + nf][i]);
        *(unsigned long long*)(vT + ((size_t)bhead * 64 + d) * 8192 + (rbase & 8191)) = p4.u;
      } else {
#pragma unroll
        for (int i = 0; i < 4; i++) {
          int gm = rbase + i;
          size_t dst = ((size_t)bhead * 8192 + (gm & 8191)) * 64 + d;
          float val = acc[mf * 4 + nf][i];
          if (part == 0) q[dst] = f2bf(val * 0.125f);
          else k[dst] = f2bf(val);
        }
      }
    }
}

// ------------- MFMA GEMM: gather(outh)[32768,512] @ Woutt^T + x + b -> out --
// grid (4, 256); single-buffered (measured-good form).
__global__ __launch_bounds__(256) void gemm_out_mfma(const ushort_t* __restrict__ outh,
                                                     const short* __restrict__ Wt,
                                                     const float* __restrict__ x,
                                                     const float* __restrict__ bo,
                                                     float* __restrict__ out) {
  int bn0 = blockIdx.x * 128, bm0 = blockIdx.y * 128;
  __shared__ __align__(16) short As[128 * 32];
  __shared__ __align__(16) short Bs[128 * 32];
  int t = threadIdx.x, l = t & 63, w = t >> 6;
  int wr = w >> 1, wc = w & 1;
  int arow = w * 32 + (l >> 2);
  int akoff = (l & 3) * 8;
  int gm0 = bm0 + arow, gm1 = gm0 + 16;
  const short* bg = Wt + (size_t)(bn0 + arow) * 512 + akoff;
  short* Adst = As + w * 1024;
  short* Bdst = Bs + w * 1024;
  int lr = l & 15, lk = (l >> 4) * 8;
  const short* Ard = As + (wr * 64 + lr) * 32 + lk;
  const short* Brd = Bs + (wc * 64 + lr) * 32 + lk;
  f32x4 acc[16];
#pragma unroll
  for (int i = 0; i < 16; i++) acc[i] = (f32x4){0.f, 0.f, 0.f, 0.f};
  for (int k0 = 0; k0 < 512; k0 += 32) {
    int kk = k0 + akoff;
    const ushort_t* a0 = outh + ((size_t)((gm0 >> 13) * 8 + (kk >> 6)) * 8192 + (gm0 & 8191)) * 64 + (kk & 63);
    const ushort_t* a1 = outh + ((size_t)((gm1 >> 13) * 8 + (kk >> 6)) * 8192 + (gm1 & 8191)) * 64 + (kk & 63);
    __builtin_amdgcn_global_load_lds(GPTR(a0), LPTR(Adst), 16, 0, 0);
    __builtin_amdgcn_global_load_lds(GPTR(a1), LPTR(Adst + 512), 16, 0, 0);
    __builtin_amdgcn_global_load_lds(GPTR(bg + k0), LPTR(Bdst), 16, 0, 0);
    __builtin_amdgcn_global_load_lds(GPTR(bg + k0 + 16 * 512), LPTR(Bdst + 512), 16, 0, 0);
    __syncthreads();
    short8 af[4], bf[4];
#pragma unroll
    for (int mf = 0; mf < 4; mf++) af[mf] = *(const short8*)(Ard + mf * 512);
#pragma unroll
    for (int nf = 0; nf < 4; nf++) bf[nf] = *(const short8*)(Brd + nf * 512);
#pragma unroll
    for (int mf = 0; mf < 4; mf++)
#pragma unroll
      for (int nf = 0; nf < 4; nf++)
        acc[mf * 4 + nf] = __builtin_amdgcn_mfma_f32_16x16x32_bf16(af[mf], bf[nf], acc[mf * 4 + nf], 0, 0, 0);
    __syncthreads();
  }
#pragma unroll
  for (int mf = 0; mf < 4; mf++)
#pragma unroll
    for (int nf = 0; nf < 4; nf++) {
      int gn = bn0 + wc * 64 + nf * 16 + (l & 15);
      int rbase = bm0 + wr * 64 + mf * 16 + ((l >> 4) << 2);
#pragma unroll
      for (int i = 0; i < 4; i++) {
        int gm = rbase + i;
        size_t o = (size_t)gm * 512 + gn;
        out[o] = x[o] + bo[gn] + acc[mf * 4 + nf][i];
      }
    }
}

// --------- landmarks: mean over 32 rows (vectorized; 1 wave per mi) ---------
__global__ __launch_bounds__(256) void land_kernel(const ushort_t* __restrict__ q,
                                                   const ushort_t* __restrict__ k,
                                                   float* __restrict__ qlf,
                                                   float* __restrict__ klf,
                                                   ushort_t* __restrict__ qlh,
                                                   ushort_t* __restrict__ klh) {
  int bh = blockIdx.y;
  int wv = threadIdx.x >> 6, l = threadIdx.x & 63;
  int mi = blockIdx.x * 4 + wv;
  size_t base = ((size_t)bh * 8192 + (size_t)mi * 32) * 64;
  float sq[8], sk[8];
#pragma unroll
  for (int e = 0; e < 8; e++) { sq[e] = 0.f; sk[e] = 0.f; }
#pragma unroll
  for (int j = 0; j < 4; j++) {
    uint4 uq = *(const uint4*)(q + base + (size_t)(j * 64 + l) * 8);
    uint4 uk = *(const uint4*)(k + base + (size_t)(j * 64 + l) * 8);
    const ushort_t* aq = (const ushort_t*)&uq;
    const ushort_t* ak = (const ushort_t*)&uk;
#pragma unroll
    for (int e = 0; e < 8; e++) { sq[e] += bf2f(aq[e]); sk[e] += bf2f(ak[e]); }
  }
#pragma unroll
  for (int m = 8; m < 64; m <<= 1)
#pragma unroll
    for (int e = 0; e < 8; e++) { sq[e] += __shfl_xor(sq[e], m); sk[e] += __shfl_xor(sk[e], m); }
  if (l < 8) {
    size_t o = ((size_t)bh * 256 + mi) * 64 + l * 8;
    union { ushort_t s[8]; uint4 u; } hq, hk;
#pragma unroll
    for (int e = 0; e < 8; e++) {
      float aq2 = sq[e] * (1.f / 32.f), ak2 = sk[e] * (1.f / 32.f);
      qlf[o + e] = aq2; klf[o + e] = ak2;
      hq.s[e] = f2bf(aq2); hk.s[e] = f2bf(ak2);
    }
    *(uint4*)(qlh + o) = hq.u;
    *(uint4*)(klh + o) = hk.u;
  }
}

// --------- sim2 + softmax -> x (attn2) as hi/lo bf16 [32][256][256] ---------
__global__ __launch_bounds__(256) void sim2_kernel(const float* __restrict__ ql,
                                                   const float* __restrict__ kl,
                                                   ushort_t* __restrict__ xh,
                                                   ushort_t* __restrict__ xl) {
  int bh = blockIdx.y, row = blockIdx.x, t = threadIdx.x;
  __shared__ float qrow[64];
  __shared__ float red[256];
  if (t < 64) qrow[t] = ql[((size_t)bh * 256 + row) * 64 + t];
  __syncthreads();
  const float* kr = kl + ((size_t)bh * 256 + t) * 64;
  float s = 0.f;
#pragma unroll
  for (int kd = 0; kd < 64; kd++) s = fmaf(qrow[kd], kr[kd], s);
  red[t] = s; __syncthreads();
  for (int off = 128; off > 0; off >>= 1) { if (t < off) red[t] = fmaxf(red[t], red[t + off]); __syncthreads(); }
  float mx = red[0]; __syncthreads();
  float pv = __expf(s - mx);
  red[t] = pv; __syncthreads();
  for (int off = 128; off > 0; off >>= 1) { if (t < off) red[t] += red[t + off]; __syncthreads(); }
  float pn = pv / red[0];
  size_t idx = ((size_t)bh << 16) + (size_t)row * 256 + t;
  ushort_t hi = f2bf(pn);
  xh[idx] = hi;
  xl[idx] = f2bf(pn - bf2f(hi));
}

// ------------- pinv init: abs row/col sums from hi/lo ----------------------
__global__ __launch_bounds__(256) void abssum_kernel(const ushort_t* __restrict__ xh,
                                                     const ushort_t* __restrict__ xl,
                                                     float* __restrict__ rowsum,
                                                     float* __restrict__ colsum) {
  int bh = blockIdx.x, t = threadIdx.x;
  size_t off = (size_t)bh << 16;
  float s = 0.f;
  for (int c = 0; c < 256; c++) {
    size_t i = off + (size_t)t * 256 + c;
    s += fabsf(bf2f(xh[i]) + bf2f(xl[i]));
  }
  rowsum[bh * 256 + t] = s;
  float s2 = 0.f;
  for (int r = 0; r < 256; r++) {
    size_t i = off + (size_t)r * 256 + t;
    s2 += fabsf(bf2f(xh[i]) + bf2f(xl[i]));
  }
  colsum[bh * 256 + t] = s2;
}

__global__ __launch_bounds__(256) void pinv_scale_kernel(const float* __restrict__ rowsum,
                                                         const float* __restrict__ colsum,
                                                         float* __restrict__ scl) {
  int t = threadIdx.x;
  float m1 = 0.f, m2 = 0.f;
  for (int i = t; i < 8192; i += 256) { m1 = fmaxf(m1, rowsum[i]); m2 = fmaxf(m2, colsum[i]); }
  __shared__ float r1[256], r2[256];
  r1[t] = m1; r2[t] = m2; __syncthreads();
  for (int off = 128; off > 0; off >>= 1) {
    if (t < off) { r1[t] = fmaxf(r1[t], r1[t + off]); r2[t] = fmaxf(r2[t], r2[t + off]); }
    __syncthreads();
  }
  if (t == 0) scl[0] = 1.f / (r1[0] * r2[0]);
}

// ------------- z0 = x^T*s (row hi/lo) and z0^T = x*s (hi/lo) ---------------
__global__ __launch_bounds__(256) void zinit_kernel(const ushort_t* __restrict__ xh,
                                                    const ushort_t* __restrict__ xl,
                                                    const float* __restrict__ scl,
                                                    ushort_t* __restrict__ zrh,
                                                    ushort_t* __restrict__ zrl,
                                                    ushort_t* __restrict__ zth,
                                                    ushort_t* __restrict__ ztl) {
  int bh = blockIdx.y, i = blockIdx.x, j = threadIdx.x;
  size_t off = (size_t)bh << 16;
  float s = scl[0];
  size_t src1 = off + (size_t)j * 256 + i;
  float v1 = (bf2f(xh[src1]) + bf2f(xl[src1])) * s;
  size_t dst = off + (size_t)i * 256 + j;
  ushort_t h1 = f2bf(v1);
  zrh[dst] = h1; zrl[dst] = f2bf(v1 - bf2f(h1));
  size_t src2 = off + (size_t)i * 256 + j;
  float v2 = (bf2f(xh[src2]) + bf2f(xl[src2])) * s;
  ushort_t h2 = f2bf(v2);
  zth[dst] = h2; ztl[dst] = f2bf(v2 - bf2f(h2));
}

// ------- NS split-precision MFMA GEMM on [32][256][256] hi/lo bf16 ---------
// MODE 0: E=acc;          write C rows + C^T     (A = x@z)
// MODE 1: E=acc-7Ex+15I;  write C^T only         (D = A@A-7A+15I)
// MODE 2: E=13I-acc;      write C^T only         (B3 = 13I-A@D)
// MODE 3: E=0.25*acc;     write C rows + C^T     (z' = 0.25*z@B3)
// FULL=1: hi/lo 3-MFMA split; FULL=0: bf16-only. WRLO=1: store lo arrays.
template<int MODE, int FULL, int WRLO>
__global__ __launch_bounds__(256) void bmm_ns(
    const ushort_t* __restrict__ Agh, const ushort_t* __restrict__ Agl,
    const ushort_t* __restrict__ Bgh, const ushort_t* __restrict__ Bgl,
    const ushort_t* __restrict__ Exh, const ushort_t* __restrict__ Exl,
    ushort_t* __restrict__ C1h, ushort_t* __restrict__ C1l,
    ushort_t* __restrict__ C2h, ushort_t* __restrict__ C2l) {
  __shared__ __align__(16) char smem[FULL ? 65536 : 32768];
  char* AhB = smem;
  char* BhB = smem + 16384;
  char* AlB = smem + 32768;   // only touched when FULL
  char* BlB = smem + 49152;

  int t = threadIdx.x, l = t & 63, w = t >> 6, h = l >> 5;
  int tile = blockIdx.x, bh = blockIdx.y;
  int tr = (tile >> 2) << 6, tc = (tile & 3) << 6;
  size_t off = (size_t)bh << 16;

  int id0 = w * 64 + l, id1 = id0 + 256;
  int r0 = id0 >> 3, cs0 = (id0 & 7) ^ (r0 & 7);
  int r1 = id1 >> 3, cs1 = (id1 & 7) ^ (r1 & 7);

  auto stage = [&](int s, int d) {
    int k0 = s << 6;
    int db = d * 8192;
    __builtin_amdgcn_global_load_lds(GPTR(Agh + off + (size_t)(tr + r0) * 256 + k0 + cs0 * 8), LPTR(AhB + db + w * 1024), 16, 0, 0);
    __builtin_amdgcn_global_load_lds(GPTR(Agh + off + (size_t)(tr + r1) * 256 + k0 + cs1 * 8), LPTR(AhB + db + w * 1024 + 4096), 16, 0, 0);
    __builtin_amdgcn_global_load_lds(GPTR(Bgh + off + (size_t)(tc + r0) * 256 + k0 + cs0 * 8), LPTR(BhB + db + w * 1024), 16, 0, 0);
    __builtin_amdgcn_global_load_lds(GPTR(Bgh + off + (size_t)(tc + r1) * 256 + k0 + cs1 * 8), LPTR(BhB + db + w * 1024 + 4096), 16, 0, 0);
    if (FULL) {
      __builtin_amdgcn_global_load_lds(GPTR(Agl + off + (size_t)(tr + r0) * 256 + k0 + cs0 * 8), LPTR(AlB + db + w * 1024), 16, 0, 0);
      __builtin_amdgcn_global_load_lds(GPTR(Agl + off + (size_t)(tr + r1) * 256 + k0 + cs1 * 8), LPTR(AlB + db + w * 1024 + 4096), 16, 0, 0);
      __builtin_amdgcn_global_load_lds(GPTR(Bgl + off + (size_t)(tc + r0) * 256 + k0 + cs0 * 8), LPTR(BlB + db + w * 1024), 16, 0, 0);
      __builtin_amdgcn_global_load_lds(GPTR(Bgl + off + (size_t)(tc + r1) * 256 + k0 + cs1 * 8), LPTR(BlB + db + w * 1024 + 4096), 16, 0, 0);
    }
  };

  f32x16 acc;
#pragma unroll
  for (int i = 0; i < 16; i++) acc[i] = 0.f;

  int rA = ((w >> 1) << 5) + (l & 31);
  int rB = ((w & 1) << 5) + (l & 31);
  int baA = rA << 7, baB = rB << 7;

  stage(0, 0);
  __syncthreads();
  for (int s = 0; s < 4; s++) {
    if (s < 3) stage(s + 1, (s + 1) & 1);
    int db = (s & 1) * 8192;
#pragma unroll
    for (int kk = 0; kk < 4; kk++) {
      int swA = (((kk << 1) + h) ^ (rA & 7)) << 4;
      int swB = (((kk << 1) + h) ^ (rB & 7)) << 4;
      short8 afh = *(const short8*)(AhB + db + baA + swA);
      short8 bfh = *(const short8*)(BhB + db + baB + swB);
      acc = __builtin_amdgcn_mfma_f32_32x32x16_bf16(afh, bfh, acc, 0, 0, 0);
      if (FULL) {
        short8 afl = *(const short8*)(AlB + db + baA + swA);
        short8 bfl = *(const short8*)(BlB + db + baB + swB);
        acc = __builtin_amdgcn_mfma_f32_32x32x16_bf16(afh, bfl, acc, 0, 0, 0);
        acc = __builtin_amdgcn_mfma_f32_32x32x16_bf16(afl, bfh, acc, 0, 0, 0);
      }
    }
    __syncthreads();
  }

  int qr = tr + ((w >> 1) << 5);
  int nloc = ((w & 1) << 5) + (l & 31);
  int gn = tc + nloc;
  ushort_t his[16], los[16];
  int ms[16];
#pragma unroll
  for (int reg = 0; reg < 16; reg++) {
    int m = (reg & 3) + ((reg >> 2) << 3) + (h << 2);
    int gm = qr + m;
    float e = acc[reg];
    if (MODE == 1) {
      size_t ei = off + (size_t)gm * 256 + gn;
      float ex = bf2f(Exh[ei]);
      if (FULL) ex += bf2f(Exl[ei]);   // cheap path: hi only (lo may be stale)
      e = e - 7.f * ex + (gm == gn ? 15.f : 0.f);
    } else if (MODE == 2) {
      e = (gm == gn ? 13.f : 0.f) - e;
    } else if (MODE == 3) {
      e *= 0.25f;
    }
    his[reg] = f2bf(e);
    if (WRLO) los[reg] = f2bf(e - bf2f(his[reg]));
    ms[reg] = ((w >> 1) << 5) + m;
  }
  ushort_t* Whi = (ushort_t*)smem;
  ushort_t* Wlo = ((ushort_t*)smem) + 4608;
#pragma unroll
  for (int reg = 0; reg < 16; reg++) {
    Whi[nloc * 72 + ms[reg]] = his[reg];
    if (WRLO) Wlo[nloc * 72 + ms[reg]] = los[reg];
  }
  __syncthreads();
  {
    int rr = t >> 2, seg = (t & 3) << 4;
    uint4 h0 = *(const uint4*)(Whi + rr * 72 + seg);
    uint4 h1 = *(const uint4*)(Whi + rr * 72 + seg + 8);
    size_t d2 = off + (size_t)(tc + rr) * 256 + tr + seg;
    *(uint4*)(C2h + d2) = h0; *(uint4*)(C2h + d2 + 8) = h1;
    if (WRLO) {
      uint4 l0 = *(const uint4*)(Wlo + rr * 72 + seg);
      uint4 l1 = *(const uint4*)(Wlo + rr * 72 + seg + 8);
      *(uint4*)(C2l + d2) = l0; *(uint4*)(C2l + d2 + 8) = l1;
    }
  }
  if (MODE == 0 || MODE == 3) {
    __syncthreads();
#pragma unroll
    for (int reg = 0; reg < 16; reg++) {
      Whi[ms[reg] * 72 + nloc] = his[reg];
      if (WRLO) Wlo[ms[reg] * 72 + nloc] = los[reg];
    }
    __syncthreads();
    int rr = t >> 2, seg = (t & 3) << 4;
    uint4 h0 = *(const uint4*)(Whi + rr * 72 + seg);
    uint4 h1 = *(const uint4*)(Whi + rr * 72 + seg + 8);
    size_t d1 = off + (size_t)(tr + rr) * 256 + tc + seg;
    *(uint4*)(C1h + d1) = h0; *(uint4*)(C1h + d1 + 8) = h1;
    if (WRLO) {
      uint4 l0 = *(const uint4*)(Wlo + rr * 72 + seg);
      uint4 l1 = *(const uint4*)(Wlo + rr * 72 + seg + 8);
      *(uint4*)(C1l + d1) = l0; *(uint4*)(C1l + d1 + 8) = l1;
    }
  }
}

// ------------- MFMA flash: out = softmax(qsrc @ ksrc^T) @ V ----------------
// write_partial=0 additionally fuses the depthwise conv residual from convsrc
// (vT layout [bh][64][8192]) into the output store.
__global__ __launch_bounds__(256) void flash_mfma(
    const ushort_t* __restrict__ qsrc, const ushort_t* __restrict__ ksrc,
    const ushort_t* __restrict__ vts, ushort_t* __restrict__ outb,
    float* __restrict__ pOT, float* __restrict__ pM, float* __restrict__ pL,
    const ushort_t* __restrict__ convsrc, const float* __restrict__ wcv,
    int nq, int nkv, int vt_stride, int nsplit, int write_partial) {
  __shared__ __align__(16) char smem[38400];
  ushort_t* Ks = (ushort_t*)smem;
  ushort_t* Vs = (ushort_t*)(smem + 8192);

  int t = threadIdx.x, l = t & 63, w = t >> 6, h = l >> 5, ql = l & 31;
  int qtile = blockIdx.x, sp = blockIdx.y, bh = blockIdx.z;
  int chunk = nkv / nsplit;
  int kvbase = sp * chunk;
  int qg = qtile * 128 + w * 32 + ql;

  const ushort_t* qp = qsrc + ((size_t)bh * nq + qg) * 64;
  short8 qf[4];
#pragma unroll
  for (int kk = 0; kk < 4; kk++) qf[kk] = *(const short8*)(qp + kk * 16 + h * 8);

  f32x16 acc0, acc1;
#pragma unroll
  for (int i = 0; i < 16; i++) { acc0[i] = 0.f; acc1[i] = 0.f; }

  int c0 = w * 64 + l, c1 = c0 + 256;
  int r0 = c0 >> 3, s0 = ((c0 & 7) ^ (r0 & 7)) << 3;
  int r1 = c1 >> 3, s1 = ((c1 & 7) ^ (r1 & 7)) << 3;
  const ushort_t* kb = ksrc + (size_t)bh * nkv * 64;
  const ushort_t* vb = vts + (size_t)bh * 64 * vt_stride;

  float mrun = -1e30f, lrun = 0.f;
  int ntiles = chunk >> 6;
  for (int it = 0; it < ntiles; it++) {
    int kvt = kvbase + it * 64;
    __syncthreads();
    __builtin_amdgcn_global_load_lds(GPTR(kb + (size_t)(kvt + r0) * 64 + s0), LPTR(Ks + w * 512), 16, 0, 0);
    __builtin_amdgcn_global_load_lds(GPTR(kb + (size_t)(kvt + r1) * 64 + s1), LPTR(Ks + 2048 + w * 512), 16, 0, 0);
    __builtin_amdgcn_global_load_lds(GPTR(vb + (size_t)r0 * vt_stride + kvt + s0), LPTR(Vs + w * 512), 16, 0, 0);
    __builtin_amdgcn_global_load_lds(GPTR(vb + (size_t)r1 * vt_stride + kvt + s1), LPTR(Vs + 2048 + w * 512), 16, 0, 0);
    __syncthreads();

    f32x16 st0, st1;
#pragma unroll
    for (int i = 0; i < 16; i++) { st0[i] = 0.f; st1[i] = 0.f; }
#pragma unroll
    for (int kk = 0; kk < 4; kk++) {
      int ch = kk * 2 + h;
      short8 kf0 = *(const short8*)(Ks + ql * 64 + ((ch ^ (ql & 7)) << 3));
      short8 kf1 = *(const short8*)(Ks + (32 + ql) * 64 + ((ch ^ (ql & 7)) << 3));
      st0 = __builtin_amdgcn_mfma_f32_32x32x16_bf16(kf0, qf[kk], st0, 0, 0, 0);
      st1 = __builtin_amdgcn_mfma_f32_32x32x16_bf16(kf1, qf[kk], st1, 0, 0, 0);
    }

    float tm = -1e30f;
#pragma unroll
    for (int r2 = 0; r2 < 16; r2++) { tm = fmaxf(tm, st0[r2]); tm = fmaxf(tm, st1[r2]); }
    tm = fmaxf(tm, __shfl_xor(tm, 32));
    float mnew = fmaxf(mrun, tm);
    float scal = __expf(mrun - mnew);
    float tsum = 0.f;
#pragma unroll
    for (int r2 = 0; r2 < 16; r2++) {
      float p0 = __expf(st0[r2] - mnew); st0[r2] = p0; tsum += p0;
      float p1 = __expf(st1[r2] - mnew); st1[r2] = p1; tsum += p1;
    }
    tsum += __shfl_xor(tsum, 32);
    lrun = lrun * scal + tsum;
    mrun = mnew;
#pragma unroll
    for (int r2 = 0; r2 < 16; r2++) { acc0[r2] *= scal; acc1[r2] *= scal; }

#pragma unroll
    for (int nf = 0; nf < 2; nf++) {
      f32x16 stv = (nf == 0) ? st0 : st1;
      unsigned int pk[8], sw[8];
#pragma unroll
      for (int g2 = 0; g2 < 4; g2++) {
        pk[g2 * 2]     = (unsigned int)f2bf(stv[g2 * 4])     | ((unsigned int)f2bf(stv[g2 * 4 + 1]) << 16);
        pk[g2 * 2 + 1] = (unsigned int)f2bf(stv[g2 * 4 + 2]) | ((unsigned int)f2bf(stv[g2 * 4 + 3]) << 16);
      }
#pragma unroll
      for (int i2 = 0; i2 < 8; i2++) sw[i2] = (unsigned int)__shfl_xor((int)pk[i2], 32);
      union { unsigned int u[4]; short8 s; } bfr0, bfr1;
      if (h == 0) {
        bfr0.u[0] = pk[0]; bfr0.u[1] = pk[1]; bfr0.u[2] = sw[0]; bfr0.u[3] = sw[1];
        bfr1.u[0] = pk[4]; bfr1.u[1] = pk[5]; bfr1.u[2] = sw[4]; bfr1.u[3] = sw[5];
      } else {
        bfr0.u[0] = sw[2]; bfr0.u[1] = sw[3]; bfr0.u[2] = pk[2]; bfr0.u[3] = pk[3];
        bfr1.u[0] = sw[6]; bfr1.u[1] = sw[7]; bfr1.u[2] = pk[6]; bfr1.u[3] = pk[7];
      }
#pragma unroll
      for (int ks2 = 0; ks2 < 2; ks2++) {
        int ch2 = nf * 4 + ks2 * 2 + h;
        short8 vf0 = *(const short8*)(Vs + ql * 64 + ((ch2 ^ (ql & 7)) << 3));
        short8 vf1 = *(const short8*)(Vs + (32 + ql) * 64 + ((ch2 ^ (ql & 7)) << 3));
        short8 pf = ks2 ? bfr1.s : bfr0.s;
        acc0 = __builtin_amdgcn_mfma_f32_32x32x16_bf16(vf0, pf, acc0, 0, 0, 0);
        acc1 = __builtin_amdgcn_mfma_f32_32x32x16_bf16(vf1, pf, acc1, 0, 0, 0);
      }
    }
  }

  if (write_partial) {
    size_t ob = (size_t)bh * nsplit + sp;
#pragma unroll
    for (int r2 = 0; r2 < 16; r2++) {
      int row = (r2 & 3) + 8 * (r2 >> 2) + 4 * h;
      pOT[(ob * 64 + row) * nq + qg] = acc0[r2];
      pOT[(ob * 64 + 32 + row) * nq + qg] = acc1[r2];
    }
    if (h == 0) { pM[ob * nq + qg] = mrun; pL[ob * nq + qg] = lrun; }
  } else {
    // ---- fused epilogue: attn/l -> Ot (bf16), conv window -> vsb, combine ---
    float inv = 1.f / lrun;
    __syncthreads();
    ushort_t* Otb = (ushort_t*)smem;             // [64][136] bf16 (17408 B)
    ushort_t* vsb = (ushort_t*)(smem + 17408);   // [64][164] bf16 (20992 B)
#pragma unroll
    for (int r2 = 0; r2 < 16; r2++) {
      int row = (r2 & 3) + 8 * (r2 >> 2) + 4 * h;
      Otb[row * 136 + w * 32 + ql] = f2bf(acc0[r2] * inv);
      Otb[(32 + row) * 136 + w * 32 + ql] = f2bf(acc1[r2] * inv);
    }
    {
      int r = t >> 2, part = t & 3;
      const ushort_t* src = convsrc + ((size_t)bh * 64 + r) * 8192;
      int n0 = qtile * 128;
#pragma unroll
      for (int j = 0; j < 5; j++) {
        int col = part * 40 + j * 8;
        int gn = n0 - 16 + col;
        if (gn >= 0 && gn + 7 < 8192) {
          *(uint2*)&vsb[r * 164 + col] = *(const uint2*)(src + gn);
          *(uint2*)&vsb[r * 164 + col + 4] = *(const uint2*)(src + gn + 4);
        } else {
#pragma unroll
          for (int e = 0; e < 8; e++) {
            int g2 = gn + e;
            vsb[r * 164 + col + e] = (g2 >= 0 && g2 < 8192) ? src[g2] : (ushort_t)0;
          }
        }
      }
    }
    __syncthreads();
    int d = t & 63, ng = t >> 6;
    float win[64];
#pragma unroll
    for (int j2 = 0; j2 < 16; j2++) {
      uint2 u = *(const uint2*)&vsb[d * 164 + ng * 32 + j2 * 4];
      const ushort_t* us = (const ushort_t*)&u;
      win[j2 * 4 + 0] = bf2f(us[0]); win[j2 * 4 + 1] = bf2f(us[1]);
      win[j2 * 4 + 2] = bf2f(us[2]); win[j2 * 4 + 3] = bf2f(us[3]);
    }
    int hh = bh & 7;
    float o[32];
#pragma unroll
    for (int i = 0; i < 32; i++) o[i] = 0.f;
#pragma unroll
    for (int kk = 0; kk < 33; kk++) {
      float wv = wcv[hh * 33 + kk];
#pragma unroll
      for (int i = 0; i < 32; i++) o[i] = fmaf(wv, win[i + kk], o[i]);
    }
    ushort_t* op = outb + ((size_t)bh * nq + qtile * 128 + ng * 32) * 64 + d;
#pragma unroll
    for (int i = 0; i < 32; i++) {
      float attn = bf2f(Otb[d * 136 + ng * 32 + i]);
      op[(size_t)i * 64] = f2bf(attn + o[i]);
    }
  }
}

// ------------- combine split-KV partials -> T bf16 [bh][256][64] -----------
// grid (8, 32): block = (d-slice of 8, bh); 256 threads = qq. m/l reduction
// recomputed per block (16 loads/thread, trivial).
#define NSPLIT 16
__global__ __launch_bounds__(256) void flash_combine(const float* __restrict__ pOT,
                                                     const float* __restrict__ pM,
                                                     const float* __restrict__ pL,
                                                     ushort_t* __restrict__ T, int nq) {
  int d0 = blockIdx.x * 8, bh = blockIdx.y, qq = threadIdx.x;
  float ms[NSPLIT], ww[NSPLIT];
  float M = -1e30f;
#pragma unroll
  for (int s = 0; s < NSPLIT; s++) {
    ms[s] = pM[((size_t)bh * NSPLIT + s) * nq + qq];
    M = fmaxf(M, ms[s]);
  }
  float L = 0.f;
#pragma unroll
  for (int s = 0; s < NSPLIT; s++) {
    ww[s] = __expf(ms[s] - M);
    L += ww[s] * pL[((size_t)bh * NSPLIT + s) * nq + qq];
  }
  float invL = 1.f / L;
  union { ushort_t s[8]; uint4 u; } o8;
#pragma unroll
  for (int j = 0; j < 8; j++) {
    int d = d0 + j;
    float o = 0.f;
#pragma unroll
    for (int s = 0; s < NSPLIT; s++)
      o += ww[s] * pOT[(((size_t)bh * NSPLIT + s) * 64 + d) * nq + qq];
    o8.s[j] = f2bf(o * invL);
  }
  *(uint4*)(T + ((size_t)bh * nq + qq) * 64 + d0) = o8.u;
}

// ------------- U^T = (z @ T)^T : UT[bh][64][256], z from hi/lo --------------
__global__ __launch_bounds__(256) void zu_kernel(const ushort_t* __restrict__ zh,
                                                 const ushort_t* __restrict__ zl,
                                                 const ushort_t* __restrict__ T,
                                                 ushort_t* __restrict__ UT) {
  __shared__ __align__(16) ushort_t Ts[16384];   // [256][64]
  __shared__ __align__(16) ushort_t Ub[64 * 40];
  int bh = blockIdx.y, r0 = blockIdx.x * 32, t = threadIdx.x;
  {
    const uint4* src = (const uint4*)(T + ((size_t)bh << 14));
    uint4* dst = (uint4*)Ts;
    for (int i = t; i < 2048; i += 256) dst[i] = src[i];
  }
  __syncthreads();
  int rloc = t >> 3, dseg = (t & 7) << 3;
  size_t zoff = ((size_t)bh << 16) + (size_t)(r0 + rloc) * 256;
  float acc[8];
#pragma unroll
  for (int j = 0; j < 8; j++) acc[j] = 0.f;
  for (int c0 = 0; c0 < 256; c0 += 8) {
    uint4 zhv = *(const uint4*)(zh + zoff + c0);
    uint4 zlv = *(const uint4*)(zl + zoff + c0);
    const ushort_t* z8h = (const ushort_t*)&zhv;
    const ushort_t* z8l = (const ushort_t*)&zlv;
#pragma unroll
    for (int cc = 0; cc < 8; cc++) {
      float zv = bf2f(z8h[cc]) + bf2f(z8l[cc]);
      short8 tv = *(const short8*)(Ts + (c0 + cc) * 64 + dseg);
#pragma unroll
      for (int j = 0; j < 8; j++) acc[j] = fmaf(zv, bf2f((ushort_t)tv[j]), acc[j]);
    }
  }
#pragma unroll
  for (int j = 0; j < 8; j++) Ub[(dseg + j) * 40 + rloc] = f2bf(acc[j]);
  __syncthreads();
  int d = t >> 2, rseg = (t & 3) << 3;
  uint4 v = *(const uint4*)(Ub + d * 40 + rseg);
  *(uint4*)(UT + ((size_t)bh * 64 + d) * 256 + r0 + rseg) = v;
}

extern "C" void kernel_launch(void* const* d_in, const int* in_sizes, int n_in,
                              void* d_out, int out_size, void* d_ws, size_t ws_size,
                              hipStream_t stream) {
  (void)in_sizes; (void)n_in; (void)out_size; (void)ws_size;
  const float* x     = (const float*)d_in[0];
  const float* g     = (const float*)d_in[1];
  const float* be    = (const float*)d_in[2];
  const float* wqkv  = (const float*)d_in[3];
  const float* wout  = (const float*)d_in[4];
  const float* bout  = (const float*)d_in[5];
  const float* convw = (const float*)d_in[6];
  float* out = (float*)d_out;

  char* base = (char*)d_ws;
  size_t off = 0;
  auto alloc = [&](size_t bytes) -> void* {
    void* r = base + off; off = (off + bytes + 255) & ~(size_t)255; return r;
  };
  const size_t NBH = (size_t)32 * 8192 * 64;
  const size_t M2 = (size_t)32 * 256 * 256 * 2;  // one [32][256][256] bf16 = 4 MB
  ushort_t* q     = (ushort_t*)alloc(NBH * 2);
  ushort_t* k     = (ushort_t*)alloc(NBH * 2);
  ushort_t* vT    = (ushort_t*)alloc(NBH * 2);
  ushort_t* outh  = (ushort_t*)alloc(NBH * 2);
  float*    qlf   = (float*)alloc((size_t)32 * 256 * 64 * 4);
  float*    klf   = (float*)alloc((size_t)32 * 256 * 64 * 4);
  ushort_t* qlh   = (ushort_t*)alloc((size_t)32 * 256 * 64 * 2);
  ushort_t* klh   = (ushort_t*)alloc((size_t)32 * 256 * 64 * 2);
  ushort_t* xh    = (ushort_t*)alloc(M2);
  ushort_t* xl    = (ushort_t*)alloc(M2);
  ushort_t* zArh  = (ushort_t*)alloc(M2);
  ushort_t* zArl  = (ushort_t*)alloc(M2);
  ushort_t* zAth  = (ushort_t*)alloc(M2);
  ushort_t* zAtl  = (ushort_t*)alloc(M2);
  ushort_t* zBrh  = (ushort_t*)alloc(M2);
  ushort_t* zBrl  = (ushort_t*)alloc(M2);
  ushort_t* zBth  = (ushort_t*)alloc(M2);
  ushort_t* zBtl  = (ushort_t*)alloc(M2);
  ushort_t* ARh   = (ushort_t*)alloc(M2);
  ushort_t* ARl   = (ushort_t*)alloc(M2);
  ushort_t* ATh   = (ushort_t*)alloc(M2);
  ushort_t* ATl   = (ushort_t*)alloc(M2);
  ushort_t* DTh   = (ushort_t*)alloc(M2);
  ushort_t* DTl   = (ushort_t*)alloc(M2);
  ushort_t* FTh   = (ushort_t*)alloc(M2);
  ushort_t* FTl   = (ushort_t*)alloc(M2);
  float*    rowsum = (float*)alloc(8192 * 4);
  float*    colsum = (float*)alloc(8192 * 4);
  float*    scl   = (float*)alloc(64);
  ushort_t* T     = (ushort_t*)alloc((size_t)32 * 256 * 64 * 2);
  ushort_t* UT    = (ushort_t*)alloc((size_t)32 * 64 * 256 * 2);
  ushort_t* Wqkvt = (ushort_t*)alloc((size_t)1536 * 512 * 2);
  ushort_t* Woutt = (ushort_t*)alloc((size_t)512 * 512 * 2);
  // Aliases: LN output Abf (33.55 MB) spans xh..zBtl (10 x 4.19 MB, written
  // only later). Flash partials (nsplit=16): pOT spans ARh..FTl (8 x 4.19 MB
  // = 33.55 MB exactly); pM/pL -> zBth/zBtl (dead after the NS loop).
  short* Abf = (short*)xh;
  float* pOT = (float*)ARh;
  float* pM  = (float*)zBth;
  float* pL  = (float*)zBtl;

  ln_bf16<<<32768, 256, 0, stream>>>(x, g, be, (ushort_t*)Abf);
  wtrans<<<dim3(8, 24), 256, 0, stream>>>(wqkv, Wqkvt, 512, 1536);
  wtrans<<<dim3(8, 8), 256, 0, stream>>>(wout, Woutt, 512, 512);
  gemm_qkv_mfma<<<dim3(256, 12), 256, 0, stream>>>(Abf, (const short*)Wqkvt, q, k, vT);
  land_kernel<<<dim3(64, 32), 256, 0, stream>>>(q, k, qlf, klf, qlh, klh);
  sim2_kernel<<<dim3(256, 32), 256, 0, stream>>>(qlf, klf, xh, xl);
  abssum_kernel<<<32, 256, 0, stream>>>(xh, xl, rowsum, colsum);
  pinv_scale_kernel<<<1, 256, 0, stream>>>(rowsum, colsum, scl);
  zinit_kernel<<<dim3(256, 32), 256, 0, stream>>>(xh, xl, scl, zArh, zArl, zAth, zAtl);

  // NS loop (x-anchored; z self-corrects): iters 0-4 bf16-only, iter 5 hi/lo.
  ushort_t *zrh = zArh, *zrl = zArl, *zth = zAth, *ztl = zAtl;
  ushort_t *nrh = zBrh, *nrl = zBrl, *nth = zBth, *ntl = zBtl;
  dim3 nsgrid(16, 32);
  for (int it = 0; it < 6; it++) {
    if (it < 5) {
      bmm_ns<0, 0, 0><<<nsgrid, 256, 0, stream>>>(xh, xl, zth, ztl, xh, xl, ARh, ARl, ATh, ATl);
      bmm_ns<1, 0, 0><<<nsgrid, 256, 0, stream>>>(ARh, ARl, ATh, ATl, ARh, ARl, DTh, DTl, DTh, DTl);
      bmm_ns<2, 0, 0><<<nsgrid, 256, 0, stream>>>(ARh, ARl, DTh, DTl, xh, xl, FTh, FTl, FTh, FTl);
      if (it == 4)
        bmm_ns<3, 0, 1><<<nsgrid, 256, 0, stream>>>(zrh, zrl, FTh, FTl, xh, xl, nrh, nrl, nth, ntl);
      else
        bmm_ns<3, 0, 0><<<nsgrid, 256, 0, stream>>>(zrh, zrl, FTh, FTl, xh, xl, nrh, nrl, nth, ntl);
    } else {
      bmm_ns<0, 1, 1><<<nsgrid, 256, 0, stream>>>(xh, xl, zth, ztl, xh, xl, ARh, ARl, ATh, ATl);
      bmm_ns<1, 1, 1><<<nsgrid, 256, 0, stream>>>(ARh, ARl, ATh, ATl, ARh, ARl, DTh, DTl, DTh, DTl);
      bmm_ns<2, 1, 1><<<nsgrid, 256, 0, stream>>>(ARh, ARl, DTh, DTl, xh, xl, FTh, FTl, FTh, FTl);
      bmm_ns<3, 1, 1><<<nsgrid, 256, 0, stream>>>(zrh, zrl, FTh, FTl, xh, xl, nrh, nrl, nth, ntl);
    }
    std::swap(zrh, nrh); std::swap(zrl, nrl);
    std::swap(zth, nth); std::swap(ztl, ntl);
  }
  // after 6 swaps final z rows = zArh/zArl. AR/AT/DT/FT + zB* dead -> flash
  // scratch.

  // T = softmax(q_land @ k^T) @ v   (split-KV 16, partials f32)
  flash_mfma<<<dim3(2, 16, 32), 256, 0, stream>>>(qlh, k, vT, T, pOT, pM, pL,
                                                  vT, convw, 256, 8192, 8192, 16, 1);
  flash_combine<<<dim3(8, 32), 256, 0, stream>>>(pOT, pM, pL, T, 256);
  // UT = (z @ T)^T
  zu_kernel<<<dim3(8, 32), 256, 0, stream>>>(zrh, zrl, T, UT);
  // outh = softmax(q @ k_land^T) @ U + depthwise conv residual (fused)
  flash_mfma<<<dim3(64, 1, 32), 256, 0, stream>>>(q, klh, UT, outh, pOT, pM, pL,
                                                  vT, convw, 8192, 256, 256, 1, 0);
  // d_out = x + concat_heads(outh) @ w_out + b_out
  gemm_out_mfma<<<dim3(4, 256), 256, 0, stream>>>(outh, (const short*)Woutt, x, bout, out);
}

// Round 16
// 590.676 us; speedup vs baseline: 1.2529x; 1.0081x over previous
//
#include <hip/hip_runtime.h>
#include <hip/hip_bf16.h>
#include <utility>

// Shapes: b=4, n=8192, d=512, h=8, dh=64, m=256 landmarks, l=32, conv k=33. bh=32.
// Round 16: abssum deleted. Row-sums of attn2 (softmax) are exactly 1, so
// scl = 1/max_colsum; colsum accumulated via atomicAdd in sim2's epilogue
// (colsum zeroed by hipMemsetAsync).

typedef unsigned short ushort_t;
typedef __attribute__((ext_vector_type(8))) short short8;
typedef __attribute__((ext_vector_type(4))) float f32x4;
typedef __attribute__((ext_vector_type(16))) float f32x16;

#define GPTR(p) ((const __attribute__((address_space(1))) void*)(p))
#define LPTR(p) ((__attribute__((address_space(3))) void*)(p))

__device__ inline float bf2f(ushort_t u) {
  union { unsigned int i; float f; } x; x.i = ((unsigned int)u) << 16; return x.f;
}
__device__ inline ushort_t f2bf(float f) {
  union { float f; unsigned int i; } x; x.f = f;
  unsigned int r = x.i + 0x7FFF + ((x.i >> 16) & 1);   // round-nearest-even
  return (ushort_t)(r >> 16);
}

// ---------------- LayerNorm -> bf16 [32768][512] ----------------
__global__ __launch_bounds__(256) void ln_bf16(const float* __restrict__ x,
                                               const float* __restrict__ g,
                                               const float* __restrict__ be,
                                               ushort_t* __restrict__ out) {
  int row = blockIdx.x; int t = threadIdx.x;
  const float* xr = x + (size_t)row * 512;
  float2 v = *(const float2*)(xr + 2 * t);
  float s = v.x + v.y, qs = v.x * v.x + v.y * v.y;
#pragma unroll
  for (int o = 32; o > 0; o >>= 1) { s += __shfl_xor(s, o); qs += __shfl_xor(qs, o); }
  __shared__ float ps[4], pq[4];
  if ((t & 63) == 0) { ps[t >> 6] = s; pq[t >> 6] = qs; }
  __syncthreads();
  s = ps[0] + ps[1] + ps[2] + ps[3];
  qs = pq[0] + pq[1] + pq[2] + pq[3];
  float mu = s * (1.f / 512.f);
  float var = qs * (1.f / 512.f) - mu * mu;
  float rstd = rsqrtf(var + 1e-5f);
  float o0 = (v.x - mu) * rstd * g[2 * t] + be[2 * t];
  float o1 = (v.y - mu) * rstd * g[2 * t + 1] + be[2 * t + 1];
  unsigned int pk = (unsigned int)f2bf(o0) | ((unsigned int)f2bf(o1) << 16);
  *(unsigned int*)(out + (size_t)row * 512 + 2 * t) = pk;
}

// ------------- weight transpose+convert: in [K][N] f32 -> out [N][K] bf16 ---
__global__ __launch_bounds__(256) void wtrans(const float* __restrict__ in,
                                              ushort_t* __restrict__ outw,
                                              int K, int N) {
  __shared__ float tile[64][65];
  int kb = blockIdx.x * 64, nb = blockIdx.y * 64, t = threadIdx.x;
  for (int i = t; i < 4096; i += 256) {
    int r = i >> 6, c = i & 63;
    tile[r][c] = in[(size_t)(kb + r) * N + nb + c];
  }
  __syncthreads();
  for (int i = t; i < 4096; i += 256) {
    int r = i >> 6, c = i & 63;
    outw[(size_t)(nb + r) * K + kb + c] = f2bf(tile[c][r]);
  }
}

// ------------- MFMA GEMM: [32768,512](bf16) @ Wt[1536,512]^T -> q/k/vT ------
// grid (256, 12); 2-phase dbuf staging; scattered epilogue (proven form).
__global__ __launch_bounds__(256) void gemm_qkv_mfma(const short* __restrict__ Abf,
                                                     const short* __restrict__ Wt,
                                                     ushort_t* __restrict__ q,
                                                     ushort_t* __restrict__ k,
                                                     ushort_t* __restrict__ vT) {
  int bm0 = blockIdx.x * 128, bn0 = blockIdx.y * 128;
  __shared__ __align__(16) short As[2 * 4096];
  __shared__ __align__(16) short Bs[2 * 4096];
  int t = threadIdx.x, l = t & 63, w = t >> 6;
  int wr = w >> 1, wc = w & 1;
  int arow = w * 32 + (l >> 2);
  int akoff = (l & 3) * 8;
  const short* ag = Abf + (size_t)(bm0 + arow) * 512 + akoff;
  const short* bg = Wt + (size_t)(bn0 + arow) * 512 + akoff;
  int lr = l & 15, lk = (l >> 4) * 8;

  auto stage = [&](int k0, int d) {
    short* Adst = As + d * 4096 + w * 1024;
    short* Bdst = Bs + d * 4096 + w * 1024;
    __builtin_amdgcn_global_load_lds(GPTR(ag + k0), LPTR(Adst), 16, 0, 0);
    __builtin_amdgcn_global_load_lds(GPTR(ag + k0 + 16 * 512), LPTR(Adst + 512), 16, 0, 0);
    __builtin_amdgcn_global_load_lds(GPTR(bg + k0), LPTR(Bdst), 16, 0, 0);
    __builtin_amdgcn_global_load_lds(GPTR(bg + k0 + 16 * 512), LPTR(Bdst + 512), 16, 0, 0);
  };

  f32x4 acc[16];
#pragma unroll
  for (int i = 0; i < 16; i++) acc[i] = (f32x4){0.f, 0.f, 0.f, 0.f};

  stage(0, 0);
  __syncthreads();
  for (int s = 0; s < 16; s++) {
    if (s < 15) stage((s + 1) * 32, (s + 1) & 1);
    const short* Ard = As + (s & 1) * 4096 + (wr * 64 + lr) * 32 + lk;
    const short* Brd = Bs + (s & 1) * 4096 + (wc * 64 + lr) * 32 + lk;
    short8 af[4], bf[4];
#pragma unroll
    for (int mf = 0; mf < 4; mf++) af[mf] = *(const short8*)(Ard + mf * 512);
#pragma unroll
    for (int nf = 0; nf < 4; nf++) bf[nf] = *(const short8*)(Brd + nf * 512);
#pragma unroll
    for (int mf = 0; mf < 4; mf++)
#pragma unroll
      for (int nf = 0; nf < 4; nf++)
        acc[mf * 4 + nf] = __builtin_amdgcn_mfma_f32_16x16x32_bf16(af[mf], bf[nf], acc[mf * 4 + nf], 0, 0, 0);
    __syncthreads();
  }
#pragma unroll
  for (int mf = 0; mf < 4; mf++)
#pragma unroll
    for (int nf = 0; nf < 4; nf++) {
      int gn = bn0 + wc * 64 + nf * 16 + (l & 15);
      int part = gn >> 9, head = (gn >> 6) & 7, d = gn & 63;
      int rbase = bm0 + wr * 64 + mf * 16 + ((l >> 4) << 2);
      int bhead = (rbase >> 13) * 8 + head;
      if (part == 2) {
        union { ushort_t s[4]; unsigned long long u; } p4;
#pragma unroll
        for (int i = 0; i < 4; i++) p4.s[i] = f2bf(acc[mf * 4 + nf][i]);
        *(unsigned long long*)(vT + ((size_t)bhead * 64 + d) * 8192 + (rbase & 8191)) = p4.u;
      } else {
#pragma unroll
        for (int i = 0; i < 4; i++) {
          int gm = rbase + i;
          size_t dst = ((size_t)bhead * 8192 + (gm & 8191)) * 64 + d;
          float val = acc[mf * 4 + nf][i];
          if (part == 0) q[dst] = f2bf(val * 0.125f);
          else k[dst] = f2bf(val);
        }
      }
    }
}

// ------------- MFMA GEMM: gather(outh)[32768,512] @ Woutt^T + x + b -> out --
// grid (4, 256); single-buffered (measured-good form).
__global__ __launch_bounds__(256) void gemm_out_mfma(const ushort_t* __restrict__ outh,
                                                     const short* __restrict__ Wt,
                                                     const float* __restrict__ x,
                                                     const float* __restrict__ bo,
                                                     float* __restrict__ out) {
  int bn0 = blockIdx.x * 128, bm0 = blockIdx.y * 128;
  __shared__ __align__(16) short As[128 * 32];
  __shared__ __align__(16) short Bs[128 * 32];
  int t = threadIdx.x, l = t & 63, w = t >> 6;
  int wr = w >> 1, wc = w & 1;
  int arow = w * 32 + (l >> 2);
  int akoff = (l & 3) * 8;
  int gm0 = bm0 + arow, gm1 = gm0 + 16;
  const short* bg = Wt + (size_t)(bn0 + arow) * 512 + akoff;
  short* Adst = As + w * 1024;
  short* Bdst = Bs + w * 1024;
  int lr = l & 15, lk = (l >> 4) * 8;
  const short* Ard = As + (wr * 64 + lr) * 32 + lk;
  const short* Brd = Bs + (wc * 64 + lr) * 32 + lk;
  f32x4 acc[16];
#pragma unroll
  for (int i = 0; i < 16; i++) acc[i] = (f32x4){0.f, 0.f, 0.f, 0.f};
  for (int k0 = 0; k0 < 512; k0 += 32) {
    int kk = k0 + akoff;
    const ushort_t* a0 = outh + ((size_t)((gm0 >> 13) * 8 + (kk >> 6)) * 8192 + (gm0 & 8191)) * 64 + (kk & 63);
    const ushort_t* a1 = outh + ((size_t)((gm1 >> 13) * 8 + (kk >> 6)) * 8192 + (gm1 & 8191)) * 64 + (kk & 63);
    __builtin_amdgcn_global_load_lds(GPTR(a0), LPTR(Adst), 16, 0, 0);
    __builtin_amdgcn_global_load_lds(GPTR(a1), LPTR(Adst + 512), 16, 0, 0);
    __builtin_amdgcn_global_load_lds(GPTR(bg + k0), LPTR(Bdst), 16, 0, 0);
    __builtin_amdgcn_global_load_lds(GPTR(bg + k0 + 16 * 512), LPTR(Bdst + 512), 16, 0, 0);
    __syncthreads();
    short8 af[4], bf[4];
#pragma unroll
    for (int mf = 0; mf < 4; mf++) af[mf] = *(const short8*)(Ard + mf * 512);
#pragma unroll
    for (int nf = 0; nf < 4; nf++) bf[nf] = *(const short8*)(Brd + nf * 512);
#pragma unroll
    for (int mf = 0; mf < 4; mf++)
#pragma unroll
      for (int nf = 0; nf < 4; nf++)
        acc[mf * 4 + nf] = __builtin_amdgcn_mfma_f32_16x16x32_bf16(af[mf], bf[nf], acc[mf * 4 + nf], 0, 0, 0);
    __syncthreads();
  }
#pragma unroll
  for (int mf = 0; mf < 4; mf++)
#pragma unroll
    for (int nf = 0; nf < 4; nf++) {
      int gn = bn0 + wc * 64 + nf * 16 + (l & 15);
      int rbase = bm0 + wr * 64 + mf * 16 + ((l >> 4) << 2);
#pragma unroll
      for (int i = 0; i < 4; i++) {
        int gm = rbase + i;
        size_t o = (size_t)gm * 512 + gn;
        out[o] = x[o] + bo[gn] + acc[mf * 4 + nf][i];
      }
    }
}

// --------- landmarks: mean over 32 rows (vectorized; 1 wave per mi) ---------
__global__ __launch_bounds__(256) void land_kernel(const ushort_t* __restrict__ q,
                                                   const ushort_t* __restrict__ k,
                                                   float* __restrict__ qlf,
                                                   float* __restrict__ klf,
                                                   ushort_t* __restrict__ qlh,
                                                   ushort_t* __restrict__ klh) {
  int bh = blockIdx.y;
  int wv = threadIdx.x >> 6, l = threadIdx.x & 63;
  int mi = blockIdx.x * 4 + wv;
  size_t base = ((size_t)bh * 8192 + (size_t)mi * 32) * 64;
  float sq[8], sk[8];
#pragma unroll
  for (int e = 0; e < 8; e++) { sq[e] = 0.f; sk[e] = 0.f; }
#pragma unroll
  for (int j = 0; j < 4; j++) {
    uint4 uq = *(const uint4*)(q + base + (size_t)(j * 64 + l) * 8);
    uint4 uk = *(const uint4*)(k + base + (size_t)(j * 64 + l) * 8);
    const ushort_t* aq = (const ushort_t*)&uq;
    const ushort_t* ak = (const ushort_t*)&uk;
#pragma unroll
    for (int e = 0; e < 8; e++) { sq[e] += bf2f(aq[e]); sk[e] += bf2f(ak[e]); }
  }
#pragma unroll
  for (int m = 8; m < 64; m <<= 1)
#pragma unroll
    for (int e = 0; e < 8; e++) { sq[e] += __shfl_xor(sq[e], m); sk[e] += __shfl_xor(sk[e], m); }
  if (l < 8) {
    size_t o = ((size_t)bh * 256 + mi) * 64 + l * 8;
    union { ushort_t s[8]; uint4 u; } hq, hk;
#pragma unroll
    for (int e = 0; e < 8; e++) {
      float aq2 = sq[e] * (1.f / 32.f), ak2 = sk[e] * (1.f / 32.f);
      qlf[o + e] = aq2; klf[o + e] = ak2;
      hq.s[e] = f2bf(aq2); hk.s[e] = f2bf(ak2);
    }
    *(uint4*)(qlh + o) = hq.u;
    *(uint4*)(klh + o) = hk.u;
  }
}

// --------- sim2 + softmax -> x (attn2) hi/lo bf16; colsum via atomicAdd -----
__global__ __launch_bounds__(256) void sim2_kernel(const float* __restrict__ ql,
                                                   const float* __restrict__ kl,
                                                   ushort_t* __restrict__ xh,
                                                   ushort_t* __restrict__ xl,
                                                   float* __restrict__ colsum) {
  int bh = blockIdx.y, row = blockIdx.x, t = threadIdx.x;
  __shared__ float qrow[64];
  __shared__ float red[256];
  if (t < 64) qrow[t] = ql[((size_t)bh * 256 + row) * 64 + t];
  __syncthreads();
  const float* kr = kl + ((size_t)bh * 256 + t) * 64;
  float s = 0.f;
#pragma unroll
  for (int kd = 0; kd < 64; kd++) s = fmaf(qrow[kd], kr[kd], s);
  red[t] = s; __syncthreads();
  for (int off = 128; off > 0; off >>= 1) { if (t < off) red[t] = fmaxf(red[t], red[t + off]); __syncthreads(); }
  float mx = red[0]; __syncthreads();
  float pv = __expf(s - mx);
  red[t] = pv; __syncthreads();
  for (int off = 128; off > 0; off >>= 1) { if (t < off) red[t] += red[t + off]; __syncthreads(); }
  float pn = pv / red[0];
  size_t idx = ((size_t)bh << 16) + (size_t)row * 256 + t;
  ushort_t hi = f2bf(pn);
  xh[idx] = hi;
  xl[idx] = f2bf(pn - bf2f(hi));
  atomicAdd(&colsum[bh * 256 + t], pn);
}

// ------------- pinv scale: scl = 1/max_colsum (rowsum of softmax == 1) ------
__global__ __launch_bounds__(256) void pinv_scale_kernel(const float* __restrict__ colsum,
                                                         float* __restrict__ scl) {
  int t = threadIdx.x;
  float m2 = 0.f;
  for (int i = t; i < 8192; i += 256) m2 = fmaxf(m2, colsum[i]);
  __shared__ float r2[256];
  r2[t] = m2; __syncthreads();
  for (int off = 128; off > 0; off >>= 1) {
    if (t < off) r2[t] = fmaxf(r2[t], r2[t + off]);
    __syncthreads();
  }
  if (t == 0) scl[0] = 1.f / r2[0];
}

// ------------- z0 = x^T*s (row hi/lo) and z0^T = x*s (hi/lo) ---------------
__global__ __launch_bounds__(256) void zinit_kernel(const ushort_t* __restrict__ xh,
                                                    const ushort_t* __restrict__ xl,
                                                    const float* __restrict__ scl,
                                                    ushort_t* __restrict__ zrh,
                                                    ushort_t* __restrict__ zrl,
                                                    ushort_t* __restrict__ zth,
                                                    ushort_t* __restrict__ ztl) {
  int bh = blockIdx.y, i = blockIdx.x, j = threadIdx.x;
  size_t off = (size_t)bh << 16;
  float s = scl[0];
  size_t src1 = off + (size_t)j * 256 + i;
  float v1 = (bf2f(xh[src1]) + bf2f(xl[src1])) * s;
  size_t dst = off + (size_t)i * 256 + j;
  ushort_t h1 = f2bf(v1);
  zrh[dst] = h1; zrl[dst] = f2bf(v1 - bf2f(h1));
  size_t src2 = off + (size_t)i * 256 + j;
  float v2 = (bf2f(xh[src2]) + bf2f(xl[src2])) * s;
  ushort_t h2 = f2bf(v2);
  zth[dst] = h2; ztl[dst] = f2bf(v2 - bf2f(h2));
}

// ------- NS split-precision MFMA GEMM on [32][256][256] hi/lo bf16 ---------
// MODE 0: E=acc;          write C rows + C^T     (A = x@z)
// MODE 1: E=acc-7Ex+15I;  write C^T only         (D = A@A-7A+15I)
// MODE 2: E=13I-acc;      write C^T only         (B3 = 13I-A@D)
// MODE 3: E=0.25*acc;     write C rows + C^T     (z' = 0.25*z@B3)
// FULL=1: hi/lo 3-MFMA split; FULL=0: bf16-only. WRLO=1: store lo arrays.
template<int MODE, int FULL, int WRLO>
__global__ __launch_bounds__(256) void bmm_ns(
    const ushort_t* __restrict__ Agh, const ushort_t* __restrict__ Agl,
    const ushort_t* __restrict__ Bgh, const ushort_t* __restrict__ Bgl,
    const ushort_t* __restrict__ Exh, const ushort_t* __restrict__ Exl,
    ushort_t* __restrict__ C1h, ushort_t* __restrict__ C1l,
    ushort_t* __restrict__ C2h, ushort_t* __restrict__ C2l) {
  __shared__ __align__(16) char smem[FULL ? 65536 : 32768];
  char* AhB = smem;
  char* BhB = smem + 16384;
  char* AlB = smem + 32768;   // only touched when FULL
  char* BlB = smem + 49152;

  int t = threadIdx.x, l = t & 63, w = t >> 6, h = l >> 5;
  int tile = blockIdx.x, bh = blockIdx.y;
  int tr = (tile >> 2) << 6, tc = (tile & 3) << 6;
  size_t off = (size_t)bh << 16;

  int id0 = w * 64 + l, id1 = id0 + 256;
  int r0 = id0 >> 3, cs0 = (id0 & 7) ^ (r0 & 7);
  int r1 = id1 >> 3, cs1 = (id1 & 7) ^ (r1 & 7);

  auto stage = [&](int s, int d) {
    int k0 = s << 6;
    int db = d * 8192;
    __builtin_amdgcn_global_load_lds(GPTR(Agh + off + (size_t)(tr + r0) * 256 + k0 + cs0 * 8), LPTR(AhB + db + w * 1024), 16, 0, 0);
    __builtin_amdgcn_global_load_lds(GPTR(Agh + off + (size_t)(tr + r1) * 256 + k0 + cs1 * 8), LPTR(AhB + db + w * 1024 + 4096), 16, 0, 0);
    __builtin_amdgcn_global_load_lds(GPTR(Bgh + off + (size_t)(tc + r0) * 256 + k0 + cs0 * 8), LPTR(BhB + db + w * 1024), 16, 0, 0);
    __builtin_amdgcn_global_load_lds(GPTR(Bgh + off + (size_t)(tc + r1) * 256 + k0 + cs1 * 8), LPTR(BhB + db + w * 1024 + 4096), 16, 0, 0);
    if (FULL) {
      __builtin_amdgcn_global_load_lds(GPTR(Agl + off + (size_t)(tr + r0) * 256 + k0 + cs0 * 8), LPTR(AlB + db + w * 1024), 16, 0, 0);
      __builtin_amdgcn_global_load_lds(GPTR(Agl + off + (size_t)(tr + r1) * 256 + k0 + cs1 * 8), LPTR(AlB + db + w * 1024 + 4096), 16, 0, 0);
      __builtin_amdgcn_global_load_lds(GPTR(Bgl + off + (size_t)(tc + r0) * 256 + k0 + cs0 * 8), LPTR(BlB + db + w * 1024), 16, 0, 0);
      __builtin_amdgcn_global_load_lds(GPTR(Bgl + off + (size_t)(tc + r1) * 256 + k0 + cs1 * 8), LPTR(BlB + db + w * 1024 + 4096), 16, 0, 0);
    }
  };

  f32x16 acc;
#pragma unroll
  for (int i = 0; i < 16; i++) acc[i] = 0.f;

  int rA = ((w >> 1) << 5) + (l & 31);
  int rB = ((w & 1) << 5) + (l & 31);
  int baA = rA << 7, baB = rB << 7;

  stage(0, 0);
  __syncthreads();
  for (int s = 0; s < 4; s++) {
    if (s < 3) stage(s + 1, (s + 1) & 1);
    int db = (s & 1) * 8192;
#pragma unroll
    for (int kk = 0; kk < 4; kk++) {
      int swA = (((kk << 1) + h) ^ (rA & 7)) << 4;
      int swB = (((kk << 1) + h) ^ (rB & 7)) << 4;
      short8 afh = *(const short8*)(AhB + db + baA + swA);
      short8 bfh = *(const short8*)(BhB + db + baB + swB);
      acc = __builtin_amdgcn_mfma_f32_32x32x16_bf16(afh, bfh, acc, 0, 0, 0);
      if (FULL) {
        short8 afl = *(const short8*)(AlB + db + baA + swA);
        short8 bfl = *(const short8*)(BlB + db + baB + swB);
        acc = __builtin_amdgcn_mfma_f32_32x32x16_bf16(afh, bfl, acc, 0, 0, 0);
        acc = __builtin_amdgcn_mfma_f32_32x32x16_bf16(afl, bfh, acc, 0, 0, 0);
      }
    }
    __syncthreads();
  }

  int qr = tr + ((w >> 1) << 5);
  int nloc = ((w & 1) << 5) + (l & 31);
  int gn = tc + nloc;
  ushort_t his[16], los[16];
  int ms[16];
#pragma unroll
  for (int reg = 0; reg < 16; reg++) {
    int m = (reg & 3) + ((reg >> 2) << 3) + (h << 2);
    int gm = qr + m;
    float e = acc[reg];
    if (MODE == 1) {
      size_t ei = off + (size_t)gm * 256 + gn;
      float ex = bf2f(Exh[ei]);
      if (FULL) ex += bf2f(Exl[ei]);   // cheap path: hi only (lo may be stale)
      e = e - 7.f * ex + (gm == gn ? 15.f : 0.f);
    } else if (MODE == 2) {
      e = (gm == gn ? 13.f : 0.f) - e;
    } else if (MODE == 3) {
      e *= 0.25f;
    }
    his[reg] = f2bf(e);
    if (WRLO) los[reg] = f2bf(e - bf2f(his[reg]));
    ms[reg] = ((w >> 1) << 5) + m;
  }
  ushort_t* Whi = (ushort_t*)smem;
  ushort_t* Wlo = ((ushort_t*)smem) + 4608;
#pragma unroll
  for (int reg = 0; reg < 16; reg++) {
    Whi[nloc * 72 + ms[reg]] = his[reg];
    if (WRLO) Wlo[nloc * 72 + ms[reg]] = los[reg];
  }
  __syncthreads();
  {
    int rr = t >> 2, seg = (t & 3) << 4;
    uint4 h0 = *(const uint4*)(Whi + rr * 72 + seg);
    uint4 h1 = *(const uint4*)(Whi + rr * 72 + seg + 8);
    size_t d2 = off + (size_t)(tc + rr) * 256 + tr + seg;
    *(uint4*)(C2h + d2) = h0; *(uint4*)(C2h + d2 + 8) = h1;
    if (WRLO) {
      uint4 l0 = *(const uint4*)(Wlo + rr * 72 + seg);
      uint4 l1 = *(const uint4*)(Wlo + rr * 72 + seg + 8);
      *(uint4*)(C2l + d2) = l0; *(uint4*)(C2l + d2 + 8) = l1;
    }
  }
  if (MODE == 0 || MODE == 3) {
    __syncthreads();
#pragma unroll
    for (int reg = 0; reg < 16; reg++) {
      Whi[ms[reg] * 72 + nloc] = his[reg];
      if (WRLO) Wlo[ms[reg] * 72 + nloc] = los[reg];
    }
    __syncthreads();
    int rr = t >> 2, seg = (t & 3) << 4;
    uint4 h0 = *(const uint4*)(Whi + rr * 72 + seg);
    uint4 h1 = *(const uint4*)(Whi + rr * 72 + seg + 8);
    size_t d1 = off + (size_t)(tr + rr) * 256 + tc + seg;
    *(uint4*)(C1h + d1) = h0; *(uint4*)(C1h + d1 + 8) = h1;
    if (WRLO) {
      uint4 l0 = *(const uint4*)(Wlo + rr * 72 + seg);
      uint4 l1 = *(const uint4*)(Wlo + rr * 72 + seg + 8);
      *(uint4*)(C1l + d1) = l0; *(uint4*)(C1l + d1 + 8) = l1;
    }
  }
}

// ------------- MFMA flash: out = softmax(qsrc @ ksrc^T) @ V ----------------
// write_partial=0 additionally fuses the depthwise conv residual from convsrc
// (vT layout [bh][64][8192]) into the output store.
__global__ __launch_bounds__(256) void flash_mfma(
    const ushort_t* __restrict__ qsrc, const ushort_t* __restrict__ ksrc,
    const ushort_t* __restrict__ vts, ushort_t* __restrict__ outb,
    float* __restrict__ pOT, float* __restrict__ pM, float* __restrict__ pL,
    const ushort_t* __restrict__ convsrc, const float* __restrict__ wcv,
    int nq, int nkv, int vt_stride, int nsplit, int write_partial) {
  __shared__ __align__(16) char smem[38400];
  ushort_t* Ks = (ushort_t*)smem;
  ushort_t* Vs = (ushort_t*)(smem + 8192);

  int t = threadIdx.x, l = t & 63, w = t >> 6, h = l >> 5, ql = l & 31;
  int qtile = blockIdx.x, sp = blockIdx.y, bh = blockIdx.z;
  int chunk = nkv / nsplit;
  int kvbase = sp * chunk;
  int qg = qtile * 128 + w * 32 + ql;

  const ushort_t* qp = qsrc + ((size_t)bh * nq + qg) * 64;
  short8 qf[4];
#pragma unroll
  for (int kk = 0; kk < 4; kk++) qf[kk] = *(const short8*)(qp + kk * 16 + h * 8);

  f32x16 acc0, acc1;
#pragma unroll
  for (int i = 0; i < 16; i++) { acc0[i] = 0.f; acc1[i] = 0.f; }

  int c0 = w * 64 + l, c1 = c0 + 256;
  int r0 = c0 >> 3, s0 = ((c0 & 7) ^ (r0 & 7)) << 3;
  int r1 = c1 >> 3, s1 = ((c1 & 7) ^ (r1 & 7)) << 3;
  const ushort_t* kb = ksrc + (size_t)bh * nkv * 64;
  const ushort_t* vb = vts + (size_t)bh * 64 * vt_stride;

  float mrun = -1e30f, lrun = 0.f;
  int ntiles = chunk >> 6;
  for (int it = 0; it < ntiles; it++) {
    int kvt = kvbase + it * 64;
    __syncthreads();
    __builtin_amdgcn_global_load_lds(GPTR(kb + (size_t)(kvt + r0) * 64 + s0), LPTR(Ks + w * 512), 16, 0, 0);
    __builtin_amdgcn_global_load_lds(GPTR(kb + (size_t)(kvt + r1) * 64 + s1), LPTR(Ks + 2048 + w * 512), 16, 0, 0);
    __builtin_amdgcn_global_load_lds(GPTR(vb + (size_t)r0 * vt_stride + kvt + s0), LPTR(Vs + w * 512), 16, 0, 0);
    __builtin_amdgcn_global_load_lds(GPTR(vb + (size_t)r1 * vt_stride + kvt + s1), LPTR(Vs + 2048 + w * 512), 16, 0, 0);
    __syncthreads();

    f32x16 st0, st1;
#pragma unroll
    for (int i = 0; i < 16; i++) { st0[i] = 0.f; st1[i] = 0.f; }
#pragma unroll
    for (int kk = 0; kk < 4; kk++) {
      int ch = kk * 2 + h;
      short8 kf0 = *(const short8*)(Ks + ql * 64 + ((ch ^ (ql & 7)) << 3));
      short8 kf1 = *(const short8*)(Ks + (32 + ql) * 64 + ((ch ^ (ql & 7)) << 3));
      st0 = __builtin_amdgcn_mfma_f32_32x32x16_bf16(kf0, qf[kk], st0, 0, 0, 0);
      st1 = __builtin_amdgcn_mfma_f32_32x32x16_bf16(kf1, qf[kk], st1, 0, 0, 0);
    }

    float tm = -1e30f;
#pragma unroll
    for (int r2 = 0; r2 < 16; r2++) { tm = fmaxf(tm, st0[r2]); tm = fmaxf(tm, st1[r2]); }
    tm = fmaxf(tm, __shfl_xor(tm, 32));
    float mnew = fmaxf(mrun, tm);
    float scal = __expf(mrun - mnew);
    float tsum = 0.f;
#pragma unroll
    for (int r2 = 0; r2 < 16; r2++) {
      float p0 = __expf(st0[r2] - mnew); st0[r2] = p0; tsum += p0;
      float p1 = __expf(st1[r2] - mnew); st1[r2] = p1; tsum += p1;
    }
    tsum += __shfl_xor(tsum, 32);
    lrun = lrun * scal + tsum;
    mrun = mnew;
#pragma unroll
    for (int r2 = 0; r2 < 16; r2++) { acc0[r2] *= scal; acc1[r2] *= scal; }

#pragma unroll
    for (int nf = 0; nf < 2; nf++) {
      f32x16 stv = (nf == 0) ? st0 : st1;
      unsigned int pk[8], sw[8];
#pragma unroll
      for (int g2 = 0; g2 < 4; g2++) {
        pk[g2 * 2]     = (unsigned int)f2bf(stv[g2 * 4])     | ((unsigned int)f2bf(stv[g2 * 4 + 1]) << 16);
        pk[g2 * 2 + 1] = (unsigned int)f2bf(stv[g2 * 4 + 2]) | ((unsigned int)f2bf(stv[g2 * 4 + 3]) << 16);
      }
#pragma unroll
      for (int i2 = 0; i2 < 8; i2++) sw[i2] = (unsigned int)__shfl_xor((int)pk[i2], 32);
      union { unsigned int u[4]; short8 s; } bfr0, bfr1;
      if (h == 0) {
        bfr0.u[0] = pk[0]; bfr0.u[1] = pk[1]; bfr0.u[2] = sw[0]; bfr0.u[3] = sw[1];
        bfr1.u[0] = pk[4]; bfr1.u[1] = pk[5]; bfr1.u[2] = sw[4]; bfr1.u[3] = sw[5];
      } else {
        bfr0.u[0] = sw[2]; bfr0.u[1] = sw[3]; bfr0.u[2] = pk[2]; bfr0.u[3] = pk[3];
        bfr1.u[0] = sw[6]; bfr1.u[1] = sw[7]; bfr1.u[2] = pk[6]; bfr1.u[3] = pk[7];
      }
#pragma unroll
      for (int ks2 = 0; ks2 < 2; ks2++) {
        int ch2 = nf * 4 + ks2 * 2 + h;
        short8 vf0 = *(const short8*)(Vs + ql * 64 + ((ch2 ^ (ql & 7)) << 3));
        short8 vf1 = *(const short8*)(Vs + (32 + ql) * 64 + ((ch2 ^ (ql & 7)) << 3));
        short8 pf = ks2 ? bfr1.s : bfr0.s;
        acc0 = __builtin_amdgcn_mfma_f32_32x32x16_bf16(vf0, pf, acc0, 0, 0, 0);
        acc1 = __builtin_amdgcn_mfma_f32_32x32x16_bf16(vf1, pf, acc1, 0, 0, 0);
      }
    }
  }

  if (write_partial) {
    size_t ob = (size_t)bh * nsplit + sp;
#pragma unroll
    for (int r2 = 0; r2 < 16; r2++) {
      int row = (r2 & 3) + 8 * (r2 >> 2) + 4 * h;
      pOT[(ob * 64 + row) * nq + qg] = acc0[r2];
      pOT[(ob * 64 + 32 + row) * nq + qg] = acc1[r2];
    }
    if (h == 0) { pM[ob * nq + qg] = mrun; pL[ob * nq + qg] = lrun; }
  } else {
    // ---- fused epilogue: attn/l -> Ot (bf16), conv window -> vsb, combine ---
    float inv = 1.f / lrun;
    __syncthreads();
    ushort_t* Otb = (ushort_t*)smem;             // [64][136] bf16 (17408 B)
    ushort_t* vsb = (ushort_t*)(smem + 17408);   // [64][164] bf16 (20992 B)
#pragma unroll
    for (int r2 = 0; r2 < 16; r2++) {
      int row = (r2 & 3) + 8 * (r2 >> 2) + 4 * h;
      Otb[row * 136 + w * 32 + ql] = f2bf(acc0[r2] * inv);
      Otb[(32 + row) * 136 + w * 32 + ql] = f2bf(acc1[r2] * inv);
    }
    {
      int r = t >> 2, part = t & 3;
      const ushort_t* src = convsrc + ((size_t)bh * 64 + r) * 8192;
      int n0 = qtile * 128;
#pragma unroll
      for (int j = 0; j < 5; j++) {
        int col = part * 40 + j * 8;
        int gn = n0 - 16 + col;
        if (gn >= 0 && gn + 7 < 8192) {
          *(uint2*)&vsb[r * 164 + col] = *(const uint2*)(src + gn);
          *(uint2*)&vsb[r * 164 + col + 4] = *(const uint2*)(src + gn + 4);
        } else {
#pragma unroll
          for (int e = 0; e < 8; e++) {
            int g2 = gn + e;
            vsb[r * 164 + col + e] = (g2 >= 0 && g2 < 8192) ? src[g2] : (ushort_t)0;
          }
        }
      }
    }
    __syncthreads();
    int d = t & 63, ng = t >> 6;
    float win[64];
#pragma unroll
    for (int j2 = 0; j2 < 16; j2++) {
      uint2 u = *(const uint2*)&vsb[d * 164 + ng * 32 + j2 * 4];
      const ushort_t* us = (const ushort_t*)&u;
      win[j2 * 4 + 0] = bf2f(us[0]); win[j2 * 4 + 1] = bf2f(us[1]);
      win[j2 * 4 + 2] = bf2f(us[2]); win[j2 * 4 + 3] = bf2f(us[3]);
    }
    int hh = bh & 7;
    float o[32];
#pragma unroll
    for (int i = 0; i < 32; i++) o[i] = 0.f;
#pragma unroll
    for (int kk = 0; kk < 33; kk++) {
      float wv = wcv[hh * 33 + kk];
#pragma unroll
      for (int i = 0; i < 32; i++) o[i] = fmaf(wv, win[i + kk], o[i]);
    }
    ushort_t* op = outb + ((size_t)bh * nq + qtile * 128 + ng * 32) * 64 + d;
#pragma unroll
    for (int i = 0; i < 32; i++) {
      float attn = bf2f(Otb[d * 136 + ng * 32 + i]);
      op[(size_t)i * 64] = f2bf(attn + o[i]);
    }
  }
}

// ------------- combine split-KV partials -> T bf16 [bh][256][64] -----------
// grid (8, 32): block = (d-slice of 8, bh); 256 threads = qq.
#define NSPLIT 16
__global__ __launch_bounds__(256) void flash_combine(const float* __restrict__ pOT,
                                                     const float* __restrict__ pM,
                                                     const float* __restrict__ pL,
                                                     ushort_t* __restrict__ T, int nq) {
  int d0 = blockIdx.x * 8, bh = blockIdx.y, qq = threadIdx.x;
  float ms[NSPLIT], ww[NSPLIT];
  float M = -1e30f;
#pragma unroll
  for (int s = 0; s < NSPLIT; s++) {
    ms[s] = pM[((size_t)bh * NSPLIT + s) * nq + qq];
    M = fmaxf(M, ms[s]);
  }
  float L = 0.f;
#pragma unroll
  for (int s = 0; s < NSPLIT; s++) {
    ww[s] = __expf(ms[s] - M);
    L += ww[s] * pL[((size_t)bh * NSPLIT + s) * nq + qq];
  }
  float invL = 1.f / L;
  union { ushort_t s[8]; uint4 u; } o8;
#pragma unroll
  for (int j = 0; j < 8; j++) {
    int d = d0 + j;
    float o = 0.f;
#pragma unroll
    for (int s = 0; s < NSPLIT; s++)
      o += ww[s] * pOT[(((size_t)bh * NSPLIT + s) * 64 + d) * nq + qq];
    o8.s[j] = f2bf(o * invL);
  }
  *(uint4*)(T + ((size_t)bh * nq + qq) * 64 + d0) = o8.u;
}

// ------------- U^T = (z @ T)^T : UT[bh][64][256], z from hi/lo --------------
__global__ __launch_bounds__(256) void zu_kernel(const ushort_t* __restrict__ zh,
                                                 const ushort_t* __restrict__ zl,
                                                 const ushort_t* __restrict__ T,
                                                 ushort_t* __restrict__ UT) {
  __shared__ __align__(16) ushort_t Ts[16384];   // [256][64]
  __shared__ __align__(16) ushort_t Ub[64 * 40];
  int bh = blockIdx.y, r0 = blockIdx.x * 32, t = threadIdx.x;
  {
    const uint4* src = (const uint4*)(T + ((size_t)bh << 14));
    uint4* dst = (uint4*)Ts;
    for (int i = t; i < 2048; i += 256) dst[i] = src[i];
  }
  __syncthreads();
  int rloc = t >> 3, dseg = (t & 7) << 3;
  size_t zoff = ((size_t)bh << 16) + (size_t)(r0 + rloc) * 256;
  float acc[8];
#pragma unroll
  for (int j = 0; j < 8; j++) acc[j] = 0.f;
  for (int c0 = 0; c0 < 256; c0 += 8) {
    uint4 zhv = *(const uint4*)(zh + zoff + c0);
    uint4 zlv = *(const uint4*)(zl + zoff + c0);
    const ushort_t* z8h = (const ushort_t*)&zhv;
    const ushort_t* z8l = (const ushort_t*)&zlv;
#pragma unroll
    for (int cc = 0; cc < 8; cc++) {
      float zv = bf2f(z8h[cc]) + bf2f(z8l[cc]);
      short8 tv = *(const short8*)(Ts + (c0 + cc) * 64 + dseg);
#pragma unroll
      for (int j = 0; j < 8; j++) acc[j] = fmaf(zv, bf2f((ushort_t)tv[j]), acc[j]);
    }
  }
#pragma unroll
  for (int j = 0; j < 8; j++) Ub[(dseg + j) * 40 + rloc] = f2bf(acc[j]);
  __syncthreads();
  int d = t >> 2, rseg = (t & 3) << 3;
  uint4 v = *(const uint4*)(Ub + d * 40 + rseg);
  *(uint4*)(UT + ((size_t)bh * 64 + d) * 256 + r0 + rseg) = v;
}

extern "C" void kernel_launch(void* const* d_in, const int* in_sizes, int n_in,
                              void* d_out, int out_size, void* d_ws, size_t ws_size,
                              hipStream_t stream) {
  (void)in_sizes; (void)n_in; (void)out_size; (void)ws_size;
  const float* x     = (const float*)d_in[0];
  const float* g     = (const float*)d_in[1];
  const float* be    = (const float*)d_in[2];
  const float* wqkv  = (const float*)d_in[3];
  const float* wout  = (const float*)d_in[4];
  const float* bout  = (const float*)d_in[5];
  const float* convw = (const float*)d_in[6];
  float* out = (float*)d_out;

  char* base = (char*)d_ws;
  size_t off = 0;
  auto alloc = [&](size_t bytes) -> void* {
    void* r = base + off; off = (off + bytes + 255) & ~(size_t)255; return r;
  };
  const size_t NBH = (size_t)32 * 8192 * 64;
  const size_t M2 = (size_t)32 * 256 * 256 * 2;  // one [32][256][256] bf16 = 4 MB
  ushort_t* q     = (ushort_t*)alloc(NBH * 2);
  ushort_t* k     = (ushort_t*)alloc(NBH * 2);
  ushort_t* vT    = (ushort_t*)alloc(NBH * 2);
  ushort_t* outh  = (ushort_t*)alloc(NBH * 2);
  float*    qlf   = (float*)alloc((size_t)32 * 256 * 64 * 4);
  float*    klf   = (float*)alloc((size_t)32 * 256 * 64 * 4);
  ushort_t* qlh   = (ushort_t*)alloc((size_t)32 * 256 * 64 * 2);
  ushort_t* klh   = (ushort_t*)alloc((size_t)32 * 256 * 64 * 2);
  ushort_t* xh    = (ushort_t*)alloc(M2);
  ushort_t* xl    = (ushort_t*)alloc(M2);
  ushort_t* zArh  = (ushort_t*)alloc(M2);
  ushort_t* zArl  = (ushort_t*)alloc(M2);
  ushort_t* zAth  = (ushort_t*)alloc(M2);
  ushort_t* zAtl  = (ushort_t*)alloc(M2);
  ushort_t* zBrh  = (ushort_t*)alloc(M2);
  ushort_t* zBrl  = (ushort_t*)alloc(M2);
  ushort_t* zBth  = (ushort_t*)alloc(M2);
  ushort_t* zBtl  = (ushort_t*)alloc(M2);
  ushort_t* ARh   = (ushort_t*)alloc(M2);
  ushort_t* ARl   = (ushort_t*)alloc(M2);
  ushort_t* ATh   = (ushort_t*)alloc(M2);
  ushort_t* ATl   = (ushort_t*)alloc(M2);
  ushort_t* DTh   = (ushort_t*)alloc(M2);
  ushort_t* DTl   = (ushort_t*)alloc(M2);
  ushort_t* FTh   = (ushort_t*)alloc(M2);
  ushort_t* FTl   = (ushort_t*)alloc(M2);
  float*    colsum = (float*)alloc(8192 * 4);
  float*    scl   = (float*)alloc(64);
  ushort_t* T     = (ushort_t*)alloc((size_t)32 * 256 * 64 * 2);
  ushort_t* UT    = (ushort_t*)alloc((size_t)32 * 64 * 256 * 2);
  ushort_t* Wqkvt = (ushort_t*)alloc((size_t)1536 * 512 * 2);
  ushort_t* Woutt = (ushort_t*)alloc((size_t)512 * 512 * 2);
  // Aliases: LN output Abf (33.55 MB) spans xh..zBtl (10 x 4.19 MB, written
  // only later). Flash partials (nsplit=16): pOT spans ARh..FTl (8 x 4.19 MB
  // = 33.55 MB exactly); pM/pL -> zBth/zBtl (dead after the NS loop).
  short* Abf = (short*)xh;
  float* pOT = (float*)ARh;
  float* pM  = (float*)zBth;
  float* pL  = (float*)zBtl;

  ln_bf16<<<32768, 256, 0, stream>>>(x, g, be, (ushort_t*)Abf);
  wtrans<<<dim3(8, 24), 256, 0, stream>>>(wqkv, Wqkvt, 512, 1536);
  wtrans<<<dim3(8, 8), 256, 0, stream>>>(wout, Woutt, 512, 512);
  gemm_qkv_mfma<<<dim3(256, 12), 256, 0, stream>>>(Abf, (const short*)Wqkvt, q, k, vT);
  land_kernel<<<dim3(64, 32), 256, 0, stream>>>(q, k, qlf, klf, qlh, klh);
  hipMemsetAsync(colsum, 0, 8192 * 4, stream);
  sim2_kernel<<<dim3(256, 32), 256, 0, stream>>>(qlf, klf, xh, xl, colsum);
  pinv_scale_kernel<<<1, 256, 0, stream>>>(colsum, scl);
  zinit_kernel<<<dim3(256, 32), 256, 0, stream>>>(xh, xl, scl, zArh, zArl, zAth, zAtl);

  // NS loop (x-anchored; z self-corrects): iters 0-4 bf16-only, iter 5 hi/lo.
  ushort_t *zrh = zArh, *zrl = zArl, *zth = zAth, *ztl = zAtl;
  ushort_t *nrh = zBrh, *nrl = zBrl, *nth = zBth, *ntl = zBtl;
  dim3 nsgrid(16, 32);
  for (int it = 0; it < 6; it++) {
    if (it < 5) {
      bmm_ns<0, 0, 0><<<nsgrid, 256, 0, stream>>>(xh, xl, zth, ztl, xh, xl, ARh, ARl, ATh, ATl);
      bmm_ns<1, 0, 0><<<nsgrid, 256, 0, stream>>>(ARh, ARl, ATh, ATl, ARh, ARl, DTh, DTl, DTh, DTl);
      bmm_ns<2, 0, 0><<<nsgrid, 256, 0, stream>>>(ARh, ARl, DTh, DTl, xh, xl, FTh, FTl, FTh, FTl);
      if (it == 4)
        bmm_ns<3, 0, 1><<<nsgrid, 256, 0, stream>>>(zrh, zrl, FTh, FTl, xh, xl, nrh, nrl, nth, ntl);
      else
        bmm_ns<3, 0, 0><<<nsgrid, 256, 0, stream>>>(zrh, zrl, FTh, FTl, xh, xl, nrh, nrl, nth, ntl);
    } else {
      bmm_ns<0, 1, 1><<<nsgrid, 256, 0, stream>>>(xh, xl, zth, ztl, xh, xl, ARh, ARl, ATh, ATl);
      bmm_ns<1, 1, 1><<<nsgrid, 256, 0, stream>>>(ARh, ARl, ATh, ATl, ARh, ARl, DTh, DTl, DTh, DTl);
      bmm_ns<2, 1, 1><<<nsgrid, 256, 0, stream>>>(ARh, ARl, DTh, DTl, xh, xl, FTh, FTl, FTh, FTl);
      bmm_ns<3, 1, 1><<<nsgrid, 256, 0, stream>>>(zrh, zrl, FTh, FTl, xh, xl, nrh, nrl, nth, ntl);
    }
    std::swap(zrh, nrh); std::swap(zrl, nrl);
    std::swap(zth, nth); std::swap(ztl, ntl);
  }
  // after 6 swaps final z rows = zArh/zArl. AR/AT/DT/FT + zB* dead -> flash
  // scratch.

  // T = softmax(q_land @ k^T) @ v   (split-KV 16, partials f32)
  flash_mfma<<<dim3(2, 16, 32), 256, 0, stream>>>(qlh, k, vT, T, pOT, pM, pL,
                                                  vT, convw, 256, 8192, 8192, 16, 1);
  flash_combine<<<dim3(8, 32), 256, 0, stream>>>(pOT, pM, pL, T, 256);
  // UT = (z @ T)^T
  zu_kernel<<<dim3(8, 32), 256, 0, stream>>>(zrh, zrl, T, UT);
  // outh = softmax(q @ k_land^T) @ U + depthwise conv residual (fused)
  flash_mfma<<<dim3(64, 1, 32), 256, 0, stream>>>(q, klh, UT, outh, pOT, pM, pL,
                                                  vT, convw, 8192, 256, 256, 1, 0);
  // d_out = x + concat_heads(outh) @ w_out + b_out
  gemm_out_mfma<<<dim3(4, 256), 256, 0, stream>>>(outh, (const short*)Woutt, x, bout, out);
}

// Round 17
// 573.289 us; speedup vs baseline: 1.2909x; 1.0303x over previous
//
#include <hip/hip_runtime.h>
#include <hip/hip_bf16.h>
#include <utility>

// Shapes: b=4, n=8192, d=512, h=8, dh=64, m=256 landmarks, l=32, conv k=33. bh=32.
// Round 17: zinit -> LDS-tiled transpose (was 2B-scattered reads); WRT flag
// skips the dead transposed-z store on the final NS iteration.

typedef unsigned short ushort_t;
typedef __attribute__((ext_vector_type(8))) short short8;
typedef __attribute__((ext_vector_type(4))) float f32x4;
typedef __attribute__((ext_vector_type(16))) float f32x16;

#define GPTR(p) ((const __attribute__((address_space(1))) void*)(p))
#define LPTR(p) ((__attribute__((address_space(3))) void*)(p))

__device__ inline float bf2f(ushort_t u) {
  union { unsigned int i; float f; } x; x.i = ((unsigned int)u) << 16; return x.f;
}
__device__ inline ushort_t f2bf(float f) {
  union { float f; unsigned int i; } x; x.f = f;
  unsigned int r = x.i + 0x7FFF + ((x.i >> 16) & 1);   // round-nearest-even
  return (ushort_t)(r >> 16);
}

// ---------------- LayerNorm -> bf16 [32768][512] ----------------
__global__ __launch_bounds__(256) void ln_bf16(const float* __restrict__ x,
                                               const float* __restrict__ g,
                                               const float* __restrict__ be,
                                               ushort_t* __restrict__ out) {
  int row = blockIdx.x; int t = threadIdx.x;
  const float* xr = x + (size_t)row * 512;
  float2 v = *(const float2*)(xr + 2 * t);
  float s = v.x + v.y, qs = v.x * v.x + v.y * v.y;
#pragma unroll
  for (int o = 32; o > 0; o >>= 1) { s += __shfl_xor(s, o); qs += __shfl_xor(qs, o); }
  __shared__ float ps[4], pq[4];
  if ((t & 63) == 0) { ps[t >> 6] = s; pq[t >> 6] = qs; }
  __syncthreads();
  s = ps[0] + ps[1] + ps[2] + ps[3];
  qs = pq[0] + pq[1] + pq[2] + pq[3];
  float mu = s * (1.f / 512.f);
  float var = qs * (1.f / 512.f) - mu * mu;
  float rstd = rsqrtf(var + 1e-5f);
  float o0 = (v.x - mu) * rstd * g[2 * t] + be[2 * t];
  float o1 = (v.y - mu) * rstd * g[2 * t + 1] + be[2 * t + 1];
  unsigned int pk = (unsigned int)f2bf(o0) | ((unsigned int)f2bf(o1) << 16);
  *(unsigned int*)(out + (size_t)row * 512 + 2 * t) = pk;
}

// ------------- weight transpose+convert: in [K][N] f32 -> out [N][K] bf16 ---
__global__ __launch_bounds__(256) void wtrans(const float* __restrict__ in,
                                              ushort_t* __restrict__ outw,
                                              int K, int N) {
  __shared__ float tile[64][65];
  int kb = blockIdx.x * 64, nb = blockIdx.y * 64, t = threadIdx.x;
  for (int i = t; i < 4096; i += 256) {
    int r = i >> 6, c = i & 63;
    tile[r][c] = in[(size_t)(kb + r) * N + nb + c];
  }
  __syncthreads();
  for (int i = t; i < 4096; i += 256) {
    int r = i >> 6, c = i & 63;
    outw[(size_t)(nb + r) * K + kb + c] = f2bf(tile[c][r]);
  }
}

// ------------- MFMA GEMM: [32768,512](bf16) @ Wt[1536,512]^T -> q/k/vT ------
// grid (256, 12); 2-phase dbuf staging; scattered epilogue (proven form).
__global__ __launch_bounds__(256) void gemm_qkv_mfma(const short* __restrict__ Abf,
                                                     const short* __restrict__ Wt,
                                                     ushort_t* __restrict__ q,
                                                     ushort_t* __restrict__ k,
                                                     ushort_t* __restrict__ vT) {
  int bm0 = blockIdx.x * 128, bn0 = blockIdx.y * 128;
  __shared__ __align__(16) short As[2 * 4096];
  __shared__ __align__(16) short Bs[2 * 4096];
  int t = threadIdx.x, l = t & 63, w = t >> 6;
  int wr = w >> 1, wc = w & 1;
  int arow = w * 32 + (l >> 2);
  int akoff = (l & 3) * 8;
  const short* ag = Abf + (size_t)(bm0 + arow) * 512 + akoff;
  const short* bg = Wt + (size_t)(bn0 + arow) * 512 + akoff;
  int lr = l & 15, lk = (l >> 4) * 8;

  auto stage = [&](int k0, int d) {
    short* Adst = As + d * 4096 + w * 1024;
    short* Bdst = Bs + d * 4096 + w * 1024;
    __builtin_amdgcn_global_load_lds(GPTR(ag + k0), LPTR(Adst), 16, 0, 0);
    __builtin_amdgcn_global_load_lds(GPTR(ag + k0 + 16 * 512), LPTR(Adst + 512), 16, 0, 0);
    __builtin_amdgcn_global_load_lds(GPTR(bg + k0), LPTR(Bdst), 16, 0, 0);
    __builtin_amdgcn_global_load_lds(GPTR(bg + k0 + 16 * 512), LPTR(Bdst + 512), 16, 0, 0);
  };

  f32x4 acc[16];
#pragma unroll
  for (int i = 0; i < 16; i++) acc[i] = (f32x4){0.f, 0.f, 0.f, 0.f};

  stage(0, 0);
  __syncthreads();
  for (int s = 0; s < 16; s++) {
    if (s < 15) stage((s + 1) * 32, (s + 1) & 1);
    const short* Ard = As + (s & 1) * 4096 + (wr * 64 + lr) * 32 + lk;
    const short* Brd = Bs + (s & 1) * 4096 + (wc * 64 + lr) * 32 + lk;
    short8 af[4], bf[4];
#pragma unroll
    for (int mf = 0; mf < 4; mf++) af[mf] = *(const short8*)(Ard + mf * 512);
#pragma unroll
    for (int nf = 0; nf < 4; nf++) bf[nf] = *(const short8*)(Brd + nf * 512);
#pragma unroll
    for (int mf = 0; mf < 4; mf++)
#pragma unroll
      for (int nf = 0; nf < 4; nf++)
        acc[mf * 4 + nf] = __builtin_amdgcn_mfma_f32_16x16x32_bf16(af[mf], bf[nf], acc[mf * 4 + nf], 0, 0, 0);
    __syncthreads();
  }
#pragma unroll
  for (int mf = 0; mf < 4; mf++)
#pragma unroll
    for (int nf = 0; nf < 4; nf++) {
      int gn = bn0 + wc * 64 + nf * 16 + (l & 15);
      int part = gn >> 9, head = (gn >> 6) & 7, d = gn & 63;
      int rbase = bm0 + wr * 64 + mf * 16 + ((l >> 4) << 2);
      int bhead = (rbase >> 13) * 8 + head;
      if (part == 2) {
        union { ushort_t s[4]; unsigned long long u; } p4;
#pragma unroll
        for (int i = 0; i < 4; i++) p4.s[i] = f2bf(acc[mf * 4 + nf][i]);
        *(unsigned long long*)(vT + ((size_t)bhead * 64 + d) * 8192 + (rbase & 8191)) = p4.u;
      } else {
#pragma unroll
        for (int i = 0; i < 4; i++) {
          int gm = rbase + i;
          size_t dst = ((size_t)bhead * 8192 + (gm & 8191)) * 64 + d;
          float val = acc[mf * 4 + nf][i];
          if (part == 0) q[dst] = f2bf(val * 0.125f);
          else k[dst] = f2bf(val);
        }
      }
    }
}

// ------------- MFMA GEMM: gather(outh)[32768,512] @ Woutt^T + x + b -> out --
// grid (4, 256); single-buffered (measured-good form).
__global__ __launch_bounds__(256) void gemm_out_mfma(const ushort_t* __restrict__ outh,
                                                     const short* __restrict__ Wt,
                                                     const float* __restrict__ x,
                                                     const float* __restrict__ bo,
                                                     float* __restrict__ out) {
  int bn0 = blockIdx.x * 128, bm0 = blockIdx.y * 128;
  __shared__ __align__(16) short As[128 * 32];
  __shared__ __align__(16) short Bs[128 * 32];
  int t = threadIdx.x, l = t & 63, w = t >> 6;
  int wr = w >> 1, wc = w & 1;
  int arow = w * 32 + (l >> 2);
  int akoff = (l & 3) * 8;
  int gm0 = bm0 + arow, gm1 = gm0 + 16;
  const short* bg = Wt + (size_t)(bn0 + arow) * 512 + akoff;
  short* Adst = As + w * 1024;
  short* Bdst = Bs + w * 1024;
  int lr = l & 15, lk = (l >> 4) * 8;
  const short* Ard = As + (wr * 64 + lr) * 32 + lk;
  const short* Brd = Bs + (wc * 64 + lr) * 32 + lk;
  f32x4 acc[16];
#pragma unroll
  for (int i = 0; i < 16; i++) acc[i] = (f32x4){0.f, 0.f, 0.f, 0.f};
  for (int k0 = 0; k0 < 512; k0 += 32) {
    int kk = k0 + akoff;
    const ushort_t* a0 = outh + ((size_t)((gm0 >> 13) * 8 + (kk >> 6)) * 8192 + (gm0 & 8191)) * 64 + (kk & 63);
    const ushort_t* a1 = outh + ((size_t)((gm1 >> 13) * 8 + (kk >> 6)) * 8192 + (gm1 & 8191)) * 64 + (kk & 63);
    __builtin_amdgcn_global_load_lds(GPTR(a0), LPTR(Adst), 16, 0, 0);
    __builtin_amdgcn_global_load_lds(GPTR(a1), LPTR(Adst + 512), 16, 0, 0);
    __builtin_amdgcn_global_load_lds(GPTR(bg + k0), LPTR(Bdst), 16, 0, 0);
    __builtin_amdgcn_global_load_lds(GPTR(bg + k0 + 16 * 512), LPTR(Bdst + 512), 16, 0, 0);
    __syncthreads();
    short8 af[4], bf[4];
#pragma unroll
    for (int mf = 0; mf < 4; mf++) af[mf] = *(const short8*)(Ard + mf * 512);
#pragma unroll
    for (int nf = 0; nf < 4; nf++) bf[nf] = *(const short8*)(Brd + nf * 512);
#pragma unroll
    for (int mf = 0; mf < 4; mf++)
#pragma unroll
      for (int nf = 0; nf < 4; nf++)
        acc[mf * 4 + nf] = __builtin_amdgcn_mfma_f32_16x16x32_bf16(af[mf], bf[nf], acc[mf * 4 + nf], 0, 0, 0);
    __syncthreads();
  }
#pragma unroll
  for (int mf = 0; mf < 4; mf++)
#pragma unroll
    for (int nf = 0; nf < 4; nf++) {
      int gn = bn0 + wc * 64 + nf * 16 + (l & 15);
      int rbase = bm0 + wr * 64 + mf * 16 + ((l >> 4) << 2);
#pragma unroll
      for (int i = 0; i < 4; i++) {
        int gm = rbase + i;
        size_t o = (size_t)gm * 512 + gn;
        out[o] = x[o] + bo[gn] + acc[mf * 4 + nf][i];
      }
    }
}

// --------- landmarks: mean over 32 rows (vectorized; 1 wave per mi) ---------
__global__ __launch_bounds__(256) void land_kernel(const ushort_t* __restrict__ q,
                                                   const ushort_t* __restrict__ k,
                                                   float* __restrict__ qlf,
                                                   float* __restrict__ klf,
                                                   ushort_t* __restrict__ qlh,
                                                   ushort_t* __restrict__ klh) {
  int bh = blockIdx.y;
  int wv = threadIdx.x >> 6, l = threadIdx.x & 63;
  int mi = blockIdx.x * 4 + wv;
  size_t base = ((size_t)bh * 8192 + (size_t)mi * 32) * 64;
  float sq[8], sk[8];
#pragma unroll
  for (int e = 0; e < 8; e++) { sq[e] = 0.f; sk[e] = 0.f; }
#pragma unroll
  for (int j = 0; j < 4; j++) {
    uint4 uq = *(const uint4*)(q + base + (size_t)(j * 64 + l) * 8);
    uint4 uk = *(const uint4*)(k + base + (size_t)(j * 64 + l) * 8);
    const ushort_t* aq = (const ushort_t*)&uq;
    const ushort_t* ak = (const ushort_t*)&uk;
#pragma unroll
    for (int e = 0; e < 8; e++) { sq[e] += bf2f(aq[e]); sk[e] += bf2f(ak[e]); }
  }
#pragma unroll
  for (int m = 8; m < 64; m <<= 1)
#pragma unroll
    for (int e = 0; e < 8; e++) { sq[e] += __shfl_xor(sq[e], m); sk[e] += __shfl_xor(sk[e], m); }
  if (l < 8) {
    size_t o = ((size_t)bh * 256 + mi) * 64 + l * 8;
    union { ushort_t s[8]; uint4 u; } hq, hk;
#pragma unroll
    for (int e = 0; e < 8; e++) {
      float aq2 = sq[e] * (1.f / 32.f), ak2 = sk[e] * (1.f / 32.f);
      qlf[o + e] = aq2; klf[o + e] = ak2;
      hq.s[e] = f2bf(aq2); hk.s[e] = f2bf(ak2);
    }
    *(uint4*)(qlh + o) = hq.u;
    *(uint4*)(klh + o) = hk.u;
  }
}

// --------- sim2 + softmax -> x (attn2) hi/lo bf16; colsum via atomicAdd -----
__global__ __launch_bounds__(256) void sim2_kernel(const float* __restrict__ ql,
                                                   const float* __restrict__ kl,
                                                   ushort_t* __restrict__ xh,
                                                   ushort_t* __restrict__ xl,
                                                   float* __restrict__ colsum) {
  int bh = blockIdx.y, row = blockIdx.x, t = threadIdx.x;
  __shared__ float qrow[64];
  __shared__ float red[256];
  if (t < 64) qrow[t] = ql[((size_t)bh * 256 + row) * 64 + t];
  __syncthreads();
  const float* kr = kl + ((size_t)bh * 256 + t) * 64;
  float s = 0.f;
#pragma unroll
  for (int kd = 0; kd < 64; kd++) s = fmaf(qrow[kd], kr[kd], s);
  red[t] = s; __syncthreads();
  for (int off = 128; off > 0; off >>= 1) { if (t < off) red[t] = fmaxf(red[t], red[t + off]); __syncthreads(); }
  float mx = red[0]; __syncthreads();
  float pv = __expf(s - mx);
  red[t] = pv; __syncthreads();
  for (int off = 128; off > 0; off >>= 1) { if (t < off) red[t] += red[t + off]; __syncthreads(); }
  float pn = pv / red[0];
  size_t idx = ((size_t)bh << 16) + (size_t)row * 256 + t;
  ushort_t hi = f2bf(pn);
  xh[idx] = hi;
  xl[idx] = f2bf(pn - bf2f(hi));
  atomicAdd(&colsum[bh * 256 + t], pn);
}

// ------------- pinv scale: scl = 1/max_colsum (rowsum of softmax == 1) ------
__global__ __launch_bounds__(256) void pinv_scale_kernel(const float* __restrict__ colsum,
                                                         float* __restrict__ scl) {
  int t = threadIdx.x;
  float m2 = 0.f;
  for (int i = t; i < 8192; i += 256) m2 = fmaxf(m2, colsum[i]);
  __shared__ float r2[256];
  r2[t] = m2; __syncthreads();
  for (int off = 128; off > 0; off >>= 1) {
    if (t < off) r2[t] = fmaxf(r2[t], r2[t + off]);
    __syncthreads();
  }
  if (t == 0) scl[0] = 1.f / r2[0];
}

// ------------- z0 = x^T*s and z0^T = x*s, LDS-tiled transpose --------------
// grid (16, 32): tile (ti,tj) of 64x64; 256 threads; f32 tile in LDS.
__global__ __launch_bounds__(256) void zinit_kernel(const ushort_t* __restrict__ xh,
                                                    const ushort_t* __restrict__ xl,
                                                    const float* __restrict__ scl,
                                                    ushort_t* __restrict__ zrh,
                                                    ushort_t* __restrict__ zrl,
                                                    ushort_t* __restrict__ zth,
                                                    ushort_t* __restrict__ ztl) {
  __shared__ float tile[64][65];
  int bh = blockIdx.y, tt = blockIdx.x;
  int ti = (tt >> 2) << 6, tj = (tt & 3) << 6;
  size_t off = (size_t)bh << 16;
  float s = scl[0];
  int r = threadIdx.x >> 2, seg = (threadIdx.x & 3) << 4;
  size_t src = off + (size_t)(ti + r) * 256 + tj + seg;
  uint4 h0 = *(const uint4*)(xh + src), h1 = *(const uint4*)(xh + src + 8);
  uint4 l0 = *(const uint4*)(xl + src), l1 = *(const uint4*)(xl + src + 8);
  const ushort_t* hs0 = (const ushort_t*)&h0;
  const ushort_t* hs1 = (const ushort_t*)&h1;
  const ushort_t* ls0 = (const ushort_t*)&l0;
  const ushort_t* ls1 = (const ushort_t*)&l1;
  union { ushort_t s[8]; uint4 u; } oh0, oh1, ol0, ol1;
#pragma unroll
  for (int e = 0; e < 8; e++) {
    float v0 = (bf2f(hs0[e]) + bf2f(ls0[e])) * s;
    float v1 = (bf2f(hs1[e]) + bf2f(ls1[e])) * s;
    tile[r][seg + e] = v0;
    tile[r][seg + 8 + e] = v1;
    ushort_t a0 = f2bf(v0), a1 = f2bf(v1);
    oh0.s[e] = a0; ol0.s[e] = f2bf(v0 - bf2f(a0));
    oh1.s[e] = a1; ol1.s[e] = f2bf(v1 - bf2f(a1));
  }
  // z0T rows: same orientation as x
  *(uint4*)(zth + src) = oh0.u; *(uint4*)(zth + src + 8) = oh1.u;
  *(uint4*)(ztl + src) = ol0.u; *(uint4*)(ztl + src + 8) = ol1.u;
  __syncthreads();
  // z0 rows: transposed. out row tj+r, cols ti+seg..+16 <- tile[seg+e][r]
  size_t dst = off + (size_t)(tj + r) * 256 + ti + seg;
#pragma unroll
  for (int e = 0; e < 8; e++) {
    float w0 = tile[seg + e][r];
    float w1 = tile[seg + 8 + e][r];
    ushort_t a0 = f2bf(w0), a1 = f2bf(w1);
    oh0.s[e] = a0; ol0.s[e] = f2bf(w0 - bf2f(a0));
    oh1.s[e] = a1; ol1.s[e] = f2bf(w1 - bf2f(a1));
  }
  *(uint4*)(zrh + dst) = oh0.u; *(uint4*)(zrh + dst + 8) = oh1.u;
  *(uint4*)(zrl + dst) = ol0.u; *(uint4*)(zrl + dst + 8) = ol1.u;
}

// ------- NS split-precision MFMA GEMM on [32][256][256] hi/lo bf16 ---------
// MODE 0: E=acc;          write C rows + C^T     (A = x@z)
// MODE 1: E=acc-7Ex+15I;  write C^T only         (D = A@A-7A+15I)
// MODE 2: E=13I-acc;      write C^T only         (B3 = 13I-A@D)
// MODE 3: E=0.25*acc;     write C rows + C^T     (z' = 0.25*z@B3)
// FULL=1: hi/lo 3-MFMA split; FULL=0: bf16-only. WRLO=1: store lo arrays.
// WRT=0: skip the transposed (C2) output entirely (dead-consumer case).
template<int MODE, int FULL, int WRLO, int WRT>
__global__ __launch_bounds__(256) void bmm_ns(
    const ushort_t* __restrict__ Agh, const ushort_t* __restrict__ Agl,
    const ushort_t* __restrict__ Bgh, const ushort_t* __restrict__ Bgl,
    const ushort_t* __restrict__ Exh, const ushort_t* __restrict__ Exl,
    ushort_t* __restrict__ C1h, ushort_t* __restrict__ C1l,
    ushort_t* __restrict__ C2h, ushort_t* __restrict__ C2l) {
  __shared__ __align__(16) char smem[FULL ? 65536 : 32768];
  char* AhB = smem;
  char* BhB = smem + 16384;
  char* AlB = smem + 32768;   // only touched when FULL
  char* BlB = smem + 49152;

  int t = threadIdx.x, l = t & 63, w = t >> 6, h = l >> 5;
  int tile = blockIdx.x, bh = blockIdx.y;
  int tr = (tile >> 2) << 6, tc = (tile & 3) << 6;
  size_t off = (size_t)bh << 16;

  int id0 = w * 64 + l, id1 = id0 + 256;
  int r0 = id0 >> 3, cs0 = (id0 & 7) ^ (r0 & 7);
  int r1 = id1 >> 3, cs1 = (id1 & 7) ^ (r1 & 7);

  auto stage = [&](int s, int d) {
    int k0 = s << 6;
    int db = d * 8192;
    __builtin_amdgcn_global_load_lds(GPTR(Agh + off + (size_t)(tr + r0) * 256 + k0 + cs0 * 8), LPTR(AhB + db + w * 1024), 16, 0, 0);
    __builtin_amdgcn_global_load_lds(GPTR(Agh + off + (size_t)(tr + r1) * 256 + k0 + cs1 * 8), LPTR(AhB + db + w * 1024 + 4096), 16, 0, 0);
    __builtin_amdgcn_global_load_lds(GPTR(Bgh + off + (size_t)(tc + r0) * 256 + k0 + cs0 * 8), LPTR(BhB + db + w * 1024), 16, 0, 0);
    __builtin_amdgcn_global_load_lds(GPTR(Bgh + off + (size_t)(tc + r1) * 256 + k0 + cs1 * 8), LPTR(BhB + db + w * 1024 + 4096), 16, 0, 0);
    if (FULL) {
      __builtin_amdgcn_global_load_lds(GPTR(Agl + off + (size_t)(tr + r0) * 256 + k0 + cs0 * 8), LPTR(AlB + db + w * 1024), 16, 0, 0);
      __builtin_amdgcn_global_load_lds(GPTR(Agl + off + (size_t)(tr + r1) * 256 + k0 + cs1 * 8), LPTR(AlB + db + w * 1024 + 4096), 16, 0, 0);
      __builtin_amdgcn_global_load_lds(GPTR(Bgl + off + (size_t)(tc + r0) * 256 + k0 + cs0 * 8), LPTR(BlB + db + w * 1024), 16, 0, 0);
      __builtin_amdgcn_global_load_lds(GPTR(Bgl + off + (size_t)(tc + r1) * 256 + k0 + cs1 * 8), LPTR(BlB + db + w * 1024 + 4096), 16, 0, 0);
    }
  };

  f32x16 acc;
#pragma unroll
  for (int i = 0; i < 16; i++) acc[i] = 0.f;

  int rA = ((w >> 1) << 5) + (l & 31);
  int rB = ((w & 1) << 5) + (l & 31);
  int baA = rA << 7, baB = rB << 7;

  stage(0, 0);
  __syncthreads();
  for (int s = 0; s < 4; s++) {
    if (s < 3) stage(s + 1, (s + 1) & 1);
    int db = (s & 1) * 8192;
#pragma unroll
    for (int kk = 0; kk < 4; kk++) {
      int swA = (((kk << 1) + h) ^ (rA & 7)) << 4;
      int swB = (((kk << 1) + h) ^ (rB & 7)) << 4;
      short8 afh = *(const short8*)(AhB + db + baA + swA);
      short8 bfh = *(const short8*)(BhB + db + baB + swB);
      acc = __builtin_amdgcn_mfma_f32_32x32x16_bf16(afh, bfh, acc, 0, 0, 0);
      if (FULL) {
        short8 afl = *(const short8*)(AlB + db + baA + swA);
        short8 bfl = *(const short8*)(BlB + db + baB + swB);
        acc = __builtin_amdgcn_mfma_f32_32x32x16_bf16(afh, bfl, acc, 0, 0, 0);
        acc = __builtin_amdgcn_mfma_f32_32x32x16_bf16(afl, bfh, acc, 0, 0, 0);
      }
    }
    __syncthreads();
  }

  int qr = tr + ((w >> 1) << 5);
  int nloc = ((w & 1) << 5) + (l & 31);
  int gn = tc + nloc;
  ushort_t his[16], los[16];
  int ms[16];
#pragma unroll
  for (int reg = 0; reg < 16; reg++) {
    int m = (reg & 3) + ((reg >> 2) << 3) + (h << 2);
    int gm = qr + m;
    float e = acc[reg];
    if (MODE == 1) {
      size_t ei = off + (size_t)gm * 256 + gn;
      float ex = bf2f(Exh[ei]);
      if (FULL) ex += bf2f(Exl[ei]);   // cheap path: hi only (lo may be stale)
      e = e - 7.f * ex + (gm == gn ? 15.f : 0.f);
    } else if (MODE == 2) {
      e = (gm == gn ? 13.f : 0.f) - e;
    } else if (MODE == 3) {
      e *= 0.25f;
    }
    his[reg] = f2bf(e);
    if (WRLO) los[reg] = f2bf(e - bf2f(his[reg]));
    ms[reg] = ((w >> 1) << 5) + m;
  }
  ushort_t* Whi = (ushort_t*)smem;
  ushort_t* Wlo = ((ushort_t*)smem) + 4608;
  if (WRT) {
#pragma unroll
    for (int reg = 0; reg < 16; reg++) {
      Whi[nloc * 72 + ms[reg]] = his[reg];
      if (WRLO) Wlo[nloc * 72 + ms[reg]] = los[reg];
    }
    __syncthreads();
    {
      int rr = t >> 2, seg = (t & 3) << 4;
      uint4 h0 = *(const uint4*)(Whi + rr * 72 + seg);
      uint4 h1 = *(const uint4*)(Whi + rr * 72 + seg + 8);
      size_t d2 = off + (size_t)(tc + rr) * 256 + tr + seg;
      *(uint4*)(C2h + d2) = h0; *(uint4*)(C2h + d2 + 8) = h1;
      if (WRLO) {
        uint4 l0 = *(const uint4*)(Wlo + rr * 72 + seg);
        uint4 l1 = *(const uint4*)(Wlo + rr * 72 + seg + 8);
        *(uint4*)(C2l + d2) = l0; *(uint4*)(C2l + d2 + 8) = l1;
      }
    }
  }
  if (MODE == 0 || MODE == 3) {
    if (WRT) __syncthreads();
#pragma unroll
    for (int reg = 0; reg < 16; reg++) {
      Whi[ms[reg] * 72 + nloc] = his[reg];
      if (WRLO) Wlo[ms[reg] * 72 + nloc] = los[reg];
    }
    __syncthreads();
    int rr = t >> 2, seg = (t & 3) << 4;
    uint4 h0 = *(const uint4*)(Whi + rr * 72 + seg);
    uint4 h1 = *(const uint4*)(Whi + rr * 72 + seg + 8);
    size_t d1 = off + (size_t)(tr + rr) * 256 + tc + seg;
    *(uint4*)(C1h + d1) = h0; *(uint4*)(C1h + d1 + 8) = h1;
    if (WRLO) {
      uint4 l0 = *(const uint4*)(Wlo + rr * 72 + seg);
      uint4 l1 = *(const uint4*)(Wlo + rr * 72 + seg + 8);
      *(uint4*)(C1l + d1) = l0; *(uint4*)(C1l + d1 + 8) = l1;
    }
  }
}

// ------------- MFMA flash: out = softmax(qsrc @ ksrc^T) @ V ----------------
// write_partial=0 additionally fuses the depthwise conv residual from convsrc
// (vT layout [bh][64][8192]) into the output store.
__global__ __launch_bounds__(256) void flash_mfma(
    const ushort_t* __restrict__ qsrc, const ushort_t* __restrict__ ksrc,
    const ushort_t* __restrict__ vts, ushort_t* __restrict__ outb,
    float* __restrict__ pOT, float* __restrict__ pM, float* __restrict__ pL,
    const ushort_t* __restrict__ convsrc, const float* __restrict__ wcv,
    int nq, int nkv, int vt_stride, int nsplit, int write_partial) {
  __shared__ __align__(16) char smem[38400];
  ushort_t* Ks = (ushort_t*)smem;
  ushort_t* Vs = (ushort_t*)(smem + 8192);

  int t = threadIdx.x, l = t & 63, w = t >> 6, h = l >> 5, ql = l & 31;
  int qtile = blockIdx.x, sp = blockIdx.y, bh = blockIdx.z;
  int chunk = nkv / nsplit;
  int kvbase = sp * chunk;
  int qg = qtile * 128 + w * 32 + ql;

  const ushort_t* qp = qsrc + ((size_t)bh * nq + qg) * 64;
  short8 qf[4];
#pragma unroll
  for (int kk = 0; kk < 4; kk++) qf[kk] = *(const short8*)(qp + kk * 16 + h * 8);

  f32x16 acc0, acc1;
#pragma unroll
  for (int i = 0; i < 16; i++) { acc0[i] = 0.f; acc1[i] = 0.f; }

  int c0 = w * 64 + l, c1 = c0 + 256;
  int r0 = c0 >> 3, s0 = ((c0 & 7) ^ (r0 & 7)) << 3;
  int r1 = c1 >> 3, s1 = ((c1 & 7) ^ (r1 & 7)) << 3;
  const ushort_t* kb = ksrc + (size_t)bh * nkv * 64;
  const ushort_t* vb = vts + (size_t)bh * 64 * vt_stride;

  float mrun = -1e30f, lrun = 0.f;
  int ntiles = chunk >> 6;
  for (int it = 0; it < ntiles; it++) {
    int kvt = kvbase + it * 64;
    __syncthreads();
    __builtin_amdgcn_global_load_lds(GPTR(kb + (size_t)(kvt + r0) * 64 + s0), LPTR(Ks + w * 512), 16, 0, 0);
    __builtin_amdgcn_global_load_lds(GPTR(kb + (size_t)(kvt + r1) * 64 + s1), LPTR(Ks + 2048 + w * 512), 16, 0, 0);
    __builtin_amdgcn_global_load_lds(GPTR(vb + (size_t)r0 * vt_stride + kvt + s0), LPTR(Vs + w * 512), 16, 0, 0);
    __builtin_amdgcn_global_load_lds(GPTR(vb + (size_t)r1 * vt_stride + kvt + s1), LPTR(Vs + 2048 + w * 512), 16, 0, 0);
    __syncthreads();

    f32x16 st0, st1;
#pragma unroll
    for (int i = 0; i < 16; i++) { st0[i] = 0.f; st1[i] = 0.f; }
#pragma unroll
    for (int kk = 0; kk < 4; kk++) {
      int ch = kk * 2 + h;
      short8 kf0 = *(const short8*)(Ks + ql * 64 + ((ch ^ (ql & 7)) << 3));
      short8 kf1 = *(const short8*)(Ks + (32 + ql) * 64 + ((ch ^ (ql & 7)) << 3));
      st0 = __builtin_amdgcn_mfma_f32_32x32x16_bf16(kf0, qf[kk], st0, 0, 0, 0);
      st1 = __builtin_amdgcn_mfma_f32_32x32x16_bf16(kf1, qf[kk], st1, 0, 0, 0);
    }

    float tm = -1e30f;
#pragma unroll
    for (int r2 = 0; r2 < 16; r2++) { tm = fmaxf(tm, st0[r2]); tm = fmaxf(tm, st1[r2]); }
    tm = fmaxf(tm, __shfl_xor(tm, 32));
    float mnew = fmaxf(mrun, tm);
    float scal = __expf(mrun - mnew);
    float tsum = 0.f;
#pragma unroll
    for (int r2 = 0; r2 < 16; r2++) {
      float p0 = __expf(st0[r2] - mnew); st0[r2] = p0; tsum += p0;
      float p1 = __expf(st1[r2] - mnew); st1[r2] = p1; tsum += p1;
    }
    tsum += __shfl_xor(tsum, 32);
    lrun = lrun * scal + tsum;
    mrun = mnew;
#pragma unroll
    for (int r2 = 0; r2 < 16; r2++) { acc0[r2] *= scal; acc1[r2] *= scal; }

#pragma unroll
    for (int nf = 0; nf < 2; nf++) {
      f32x16 stv = (nf == 0) ? st0 : st1;
      unsigned int pk[8], sw[8];
#pragma unroll
      for (int g2 = 0; g2 < 4; g2++) {
        pk[g2 * 2]     = (unsigned int)f2bf(stv[g2 * 4])     | ((unsigned int)f2bf(stv[g2 * 4 + 1]) << 16);
        pk[g2 * 2 + 1] = (unsigned int)f2bf(stv[g2 * 4 + 2]) | ((unsigned int)f2bf(stv[g2 * 4 + 3]) << 16);
      }
#pragma unroll
      for (int i2 = 0; i2 < 8; i2++) sw[i2] = (unsigned int)__shfl_xor((int)pk[i2], 32);
      union { unsigned int u[4]; short8 s; } bfr0, bfr1;
      if (h == 0) {
        bfr0.u[0] = pk[0]; bfr0.u[1] = pk[1]; bfr0.u[2] = sw[0]; bfr0.u[3] = sw[1];
        bfr1.u[0] = pk[4]; bfr1.u[1] = pk[5]; bfr1.u[2] = sw[4]; bfr1.u[3] = sw[5];
      } else {
        bfr0.u[0] = sw[2]; bfr0.u[1] = sw[3]; bfr0.u[2] = pk[2]; bfr0.u[3] = pk[3];
        bfr1.u[0] = sw[6]; bfr1.u[1] = sw[7]; bfr1.u[2] = pk[6]; bfr1.u[3] = pk[7];
      }
#pragma unroll
      for (int ks2 = 0; ks2 < 2; ks2++) {
        int ch2 = nf * 4 + ks2 * 2 + h;
        short8 vf0 = *(const short8*)(Vs + ql * 64 + ((ch2 ^ (ql & 7)) << 3));
        short8 vf1 = *(const short8*)(Vs + (32 + ql) * 64 + ((ch2 ^ (ql & 7)) << 3));
        short8 pf = ks2 ? bfr1.s : bfr0.s;
        acc0 = __builtin_amdgcn_mfma_f32_32x32x16_bf16(vf0, pf, acc0, 0, 0, 0);
        acc1 = __builtin_amdgcn_mfma_f32_32x32x16_bf16(vf1, pf, acc1, 0, 0, 0);
      }
    }
  }

  if (write_partial) {
    size_t ob = (size_t)bh * nsplit + sp;
#pragma unroll
    for (int r2 = 0; r2 < 16; r2++) {
      int row = (r2 & 3) + 8 * (r2 >> 2) + 4 * h;
      pOT[(ob * 64 + row) * nq + qg] = acc0[r2];
      pOT[(ob * 64 + 32 + row) * nq + qg] = acc1[r2];
    }
    if (h == 0) { pM[ob * nq + qg] = mrun; pL[ob * nq + qg] = lrun; }
  } else {
    // ---- fused epilogue: attn/l -> Ot (bf16), conv window -> vsb, combine ---
    float inv = 1.f / lrun;
    __syncthreads();
    ushort_t* Otb = (ushort_t*)smem;             // [64][136] bf16 (17408 B)
    ushort_t* vsb = (ushort_t*)(smem + 17408);   // [64][164] bf16 (20992 B)
#pragma unroll
    for (int r2 = 0; r2 < 16; r2++) {
      int row = (r2 & 3) + 8 * (r2 >> 2) + 4 * h;
      Otb[row * 136 + w * 32 + ql] = f2bf(acc0[r2] * inv);
      Otb[(32 + row) * 136 + w * 32 + ql] = f2bf(acc1[r2] * inv);
    }
    {
      int r = t >> 2, part = t & 3;
      const ushort_t* src = convsrc + ((size_t)bh * 64 + r) * 8192;
      int n0 = qtile * 128;
#pragma unroll
      for (int j = 0; j < 5; j++) {
        int col = part * 40 + j * 8;
        int gn = n0 - 16 + col;
        if (gn >= 0 && gn + 7 < 8192) {
          *(uint2*)&vsb[r * 164 + col] = *(const uint2*)(src + gn);
          *(uint2*)&vsb[r * 164 + col + 4] = *(const uint2*)(src + gn + 4);
        } else {
#pragma unroll
          for (int e = 0; e < 8; e++) {
            int g2 = gn + e;
            vsb[r * 164 + col + e] = (g2 >= 0 && g2 < 8192) ? src[g2] : (ushort_t)0;
          }
        }
      }
    }
    __syncthreads();
    int d = t & 63, ng = t >> 6;
    float win[64];
#pragma unroll
    for (int j2 = 0; j2 < 16; j2++) {
      uint2 u = *(const uint2*)&vsb[d * 164 + ng * 32 + j2 * 4];
      const ushort_t* us = (const ushort_t*)&u;
      win[j2 * 4 + 0] = bf2f(us[0]); win[j2 * 4 + 1] = bf2f(us[1]);
      win[j2 * 4 + 2] = bf2f(us[2]); win[j2 * 4 + 3] = bf2f(us[3]);
    }
    int hh = bh & 7;
    float o[32];
#pragma unroll
    for (int i = 0; i < 32; i++) o[i] = 0.f;
#pragma unroll
    for (int kk = 0; kk < 33; kk++) {
      float wv = wcv[hh * 33 + kk];
#pragma unroll
      for (int i = 0; i < 32; i++) o[i] = fmaf(wv, win[i + kk], o[i]);
    }
    ushort_t* op = outb + ((size_t)bh * nq + qtile * 128 + ng * 32) * 64 + d;
#pragma unroll
    for (int i = 0; i < 32; i++) {
      float attn = bf2f(Otb[d * 136 + ng * 32 + i]);
      op[(size_t)i * 64] = f2bf(attn + o[i]);
    }
  }
}

// ------------- combine split-KV partials -> T bf16 [bh][256][64] -----------
// grid (8, 32): block = (d-slice of 8, bh); 256 threads = qq.
#define NSPLIT 16
__global__ __launch_bounds__(256) void flash_combine(const float* __restrict__ pOT,
                                                     const float* __restrict__ pM,
                                                     const float* __restrict__ pL,
                                                     ushort_t* __restrict__ T, int nq) {
  int d0 = blockIdx.x * 8, bh = blockIdx.y, qq = threadIdx.x;
  float ms[NSPLIT], ww[NSPLIT];
  float M = -1e30f;
#pragma unroll
  for (int s = 0; s < NSPLIT; s++) {
    ms[s] = pM[((size_t)bh * NSPLIT + s) * nq + qq];
    M = fmaxf(M, ms[s]);
  }
  float L = 0.f;
#pragma unroll
  for (int s = 0; s < NSPLIT; s++) {
    ww[s] = __expf(ms[s] - M);
    L += ww[s] * pL[((size_t)bh * NSPLIT + s) * nq + qq];
  }
  float invL = 1.f / L;
  union { ushort_t s[8]; uint4 u; } o8;
#pragma unroll
  for (int j = 0; j < 8; j++) {
    int d = d0 + j;
    float o = 0.f;
#pragma unroll
    for (int s = 0; s < NSPLIT; s++)
      o += ww[s] * pOT[(((size_t)bh * NSPLIT + s) * 64 + d) * nq + qq];
    o8.s[j] = f2bf(o * invL);
  }
  *(uint4*)(T + ((size_t)bh * nq + qq) * 64 + d0) = o8.u;
}

// ------------- U^T = (z @ T)^T : UT[bh][64][256], z from hi/lo --------------
__global__ __launch_bounds__(256) void zu_kernel(const ushort_t* __restrict__ zh,
                                                 const ushort_t* __restrict__ zl,
                                                 const ushort_t* __restrict__ T,
                                                 ushort_t* __restrict__ UT) {
  __shared__ __align__(16) ushort_t Ts[16384];   // [256][64]
  __shared__ __align__(16) ushort_t Ub[64 * 40];
  int bh = blockIdx.y, r0 = blockIdx.x * 32, t = threadIdx.x;
  {
    const uint4* src = (const uint4*)(T + ((size_t)bh << 14));
    uint4* dst = (uint4*)Ts;
    for (int i = t; i < 2048; i += 256) dst[i] = src[i];
  }
  __syncthreads();
  int rloc = t >> 3, dseg = (t & 7) << 3;
  size_t zoff = ((size_t)bh << 16) + (size_t)(r0 + rloc) * 256;
  float acc[8];
#pragma unroll
  for (int j = 0; j < 8; j++) acc[j] = 0.f;
  for (int c0 = 0; c0 < 256; c0 += 8) {
    uint4 zhv = *(const uint4*)(zh + zoff + c0);
    uint4 zlv = *(const uint4*)(zl + zoff + c0);
    const ushort_t* z8h = (const ushort_t*)&zhv;
    const ushort_t* z8l = (const ushort_t*)&zlv;
#pragma unroll
    for (int cc = 0; cc < 8; cc++) {
      float zv = bf2f(z8h[cc]) + bf2f(z8l[cc]);
      short8 tv = *(const short8*)(Ts + (c0 + cc) * 64 + dseg);
#pragma unroll
      for (int j = 0; j < 8; j++) acc[j] = fmaf(zv, bf2f((ushort_t)tv[j]), acc[j]);
    }
  }
#pragma unroll
  for (int j = 0; j < 8; j++) Ub[(dseg + j) * 40 + rloc] = f2bf(acc[j]);
  __syncthreads();
  int d = t >> 2, rseg = (t & 3) << 3;
  uint4 v = *(const uint4*)(Ub + d * 40 + rseg);
  *(uint4*)(UT + ((size_t)bh * 64 + d) * 256 + r0 + rseg) = v;
}

extern "C" void kernel_launch(void* const* d_in, const int* in_sizes, int n_in,
                              void* d_out, int out_size, void* d_ws, size_t ws_size,
                              hipStream_t stream) {
  (void)in_sizes; (void)n_in; (void)out_size; (void)ws_size;
  const float* x     = (const float*)d_in[0];
  const float* g     = (const float*)d_in[1];
  const float* be    = (const float*)d_in[2];
  const float* wqkv  = (const float*)d_in[3];
  const float* wout  = (const float*)d_in[4];
  const float* bout  = (const float*)d_in[5];
  const float* convw = (const float*)d_in[6];
  float* out = (float*)d_out;

  char* base = (char*)d_ws;
  size_t off = 0;
  auto alloc = [&](size_t bytes) -> void* {
    void* r = base + off; off = (off + bytes + 255) & ~(size_t)255; return r;
  };
  const size_t NBH = (size_t)32 * 8192 * 64;
  const size_t M2 = (size_t)32 * 256 * 256 * 2;  // one [32][256][256] bf16 = 4 MB
  ushort_t* q     = (ushort_t*)alloc(NBH * 2);
  ushort_t* k     = (ushort_t*)alloc(NBH * 2);
  ushort_t* vT    = (ushort_t*)alloc(NBH * 2);
  ushort_t* outh  = (ushort_t*)alloc(NBH * 2);
  float*    qlf   = (float*)alloc((size_t)32 * 256 * 64 * 4);
  float*    klf   = (float*)alloc((size_t)32 * 256 * 64 * 4);
  ushort_t* qlh   = (ushort_t*)alloc((size_t)32 * 256 * 64 * 2);
  ushort_t* klh   = (ushort_t*)alloc((size_t)32 * 256 * 64 * 2);
  ushort_t* xh    = (ushort_t*)alloc(M2);
  ushort_t* xl    = (ushort_t*)alloc(M2);
  ushort_t* zArh  = (ushort_t*)alloc(M2);
  ushort_t* zArl  = (ushort_t*)alloc(M2);
  ushort_t* zAth  = (ushort_t*)alloc(M2);
  ushort_t* zAtl  = (ushort_t*)alloc(M2);
  ushort_t* zBrh  = (ushort_t*)alloc(M2);
  ushort_t* zBrl  = (ushort_t*)alloc(M2);
  ushort_t* zBth  = (ushort_t*)alloc(M2);
  ushort_t* zBtl  = (ushort_t*)alloc(M2);
  ushort_t* ARh   = (ushort_t*)alloc(M2);
  ushort_t* ARl   = (ushort_t*)alloc(M2);
  ushort_t* ATh   = (ushort_t*)alloc(M2);
  ushort_t* ATl   = (ushort_t*)alloc(M2);
  ushort_t* DTh   = (ushort_t*)alloc(M2);
  ushort_t* DTl   = (ushort_t*)alloc(M2);
  ushort_t* FTh   = (ushort_t*)alloc(M2);
  ushort_t* FTl   = (ushort_t*)alloc(M2);
  float*    colsum = (float*)alloc(8192 * 4);
  float*    scl   = (float*)alloc(64);
  ushort_t* T     = (ushort_t*)alloc((size_t)32 * 256 * 64 * 2);
  ushort_t* UT    = (ushort_t*)alloc((size_t)32 * 64 * 256 * 2);
  ushort_t* Wqkvt = (ushort_t*)alloc((size_t)1536 * 512 * 2);
  ushort_t* Woutt = (ushort_t*)alloc((size_t)512 * 512 * 2);
  // Aliases: LN output Abf (33.55 MB) spans xh..zBtl (10 x 4.19 MB, written
  // only later). Flash partials (nsplit=16): pOT spans ARh..FTl (8 x 4.19 MB
  // = 33.55 MB exactly); pM/pL -> zBth/zBtl (dead after the NS loop).
  short* Abf = (short*)xh;
  float* pOT = (float*)ARh;
  float* pM  = (float*)zBth;
  float* pL  = (float*)zBtl;

  ln_bf16<<<32768, 256, 0, stream>>>(x, g, be, (ushort_t*)Abf);
  wtrans<<<dim3(8, 24), 256, 0, stream>>>(wqkv, Wqkvt, 512, 1536);
  wtrans<<<dim3(8, 8), 256, 0, stream>>>(wout, Woutt, 512, 512);
  gemm_qkv_mfma<<<dim3(256, 12), 256, 0, stream>>>(Abf, (const short*)Wqkvt, q, k, vT);
  land_kernel<<<dim3(64, 32), 256, 0, stream>>>(q, k, qlf, klf, qlh, klh);
  hipMemsetAsync(colsum, 0, 8192 * 4, stream);
  sim2_kernel<<<dim3(256, 32), 256, 0, stream>>>(qlf, klf, xh, xl, colsum);
  pinv_scale_kernel<<<1, 256, 0, stream>>>(colsum, scl);
  zinit_kernel<<<dim3(16, 32), 256, 0, stream>>>(xh, xl, scl, zArh, zArl, zAth, zAtl);

  // NS loop (x-anchored; z self-corrects): iters 0-4 bf16-only, iter 5 hi/lo.
  ushort_t *zrh = zArh, *zrl = zArl, *zth = zAth, *ztl = zAtl;
  ushort_t *nrh = zBrh, *nrl = zBrl, *nth = zBth, *ntl = zBtl;
  dim3 nsgrid(16, 32);
  for (int it = 0; it < 6; it++) {
    if (it < 5) {
      bmm_ns<0, 0, 0, 1><<<nsgrid, 256, 0, stream>>>(xh, xl, zth, ztl, xh, xl, ARh, ARl, ATh, ATl);
      bmm_ns<1, 0, 0, 1><<<nsgrid, 256, 0, stream>>>(ARh, ARl, ATh, ATl, ARh, ARl, DTh, DTl, DTh, DTl);
      bmm_ns<2, 0, 0, 1><<<nsgrid, 256, 0, stream>>>(ARh, ARl, DTh, DTl, xh, xl, FTh, FTl, FTh, FTl);
      if (it == 4)
        bmm_ns<3, 0, 1, 1><<<nsgrid, 256, 0, stream>>>(zrh, zrl, FTh, FTl, xh, xl, nrh, nrl, nth, ntl);
      else
        bmm_ns<3, 0, 0, 1><<<nsgrid, 256, 0, stream>>>(zrh, zrl, FTh, FTl, xh, xl, nrh, nrl, nth, ntl);
    } else {
      bmm_ns<0, 1, 1, 1><<<nsgrid, 256, 0, stream>>>(xh, xl, zth, ztl, xh, xl, ARh, ARl, ATh, ATl);
      bmm_ns<1, 1, 1, 1><<<nsgrid, 256, 0, stream>>>(ARh, ARl, ATh, ATl, ARh, ARl, DTh, DTl, DTh, DTl);
      bmm_ns<2, 1, 1, 1><<<nsgrid, 256, 0, stream>>>(ARh, ARl, DTh, DTl, xh, xl, FTh, FTl, FTh, FTl);
      // final z': transposed output is dead (only z rows feed zu_kernel)
      bmm_ns<3, 1, 1, 0><<<nsgrid, 256, 0, stream>>>(zrh, zrl, FTh, FTl, xh, xl, nrh, nrl, nth, ntl);
    }
    std::swap(zrh, nrh); std::swap(zrl, nrl);
    std::swap(zth, nth); std::swap(ztl, ntl);
  }
  // after 6 swaps final z rows = zArh/zArl. AR/AT/DT/FT + zB* dead -> flash
  // scratch.

  // T = softmax(q_land @ k^T) @ v   (split-KV 16, partials f32)
  flash_mfma<<<dim3(2, 16, 32), 256, 0, stream>>>(qlh, k, vT, T, pOT, pM, pL,
                                                  vT, convw, 256, 8192, 8192, 16, 1);
  flash_combine<<<dim3(8, 32), 256, 0, stream>>>(pOT, pM, pL, T, 256);
  // UT = (z @ T)^T
  zu_kernel<<<dim3(8, 32), 256, 0, stream>>>(zrh, zrl, T, UT);
  // outh = softmax(q @ k_land^T) @ U + depthwise conv residual (fused)
  flash_mfma<<<dim3(64, 1, 32), 256, 0, stream>>>(q, klh, UT, outh, pOT, pM, pL,
                                                  vT, convw, 8192, 256, 256, 1, 0);
  // d_out = x + concat_heads(outh) @ w_out + b_out
  gemm_out_mfma<<<dim3(4, 256), 256, 0, stream>>>(outh, (const short*)Woutt, x, bout, out);
}